// Round 1
// baseline (2763.843 us; speedup 1.0000x reference)
//
#include <hip/hip_runtime.h>

#define NN 2048      // sequence length
#define DDIM 128     // d_model
#define NHEAD 4
#define DH 32        // per-head dim
#define NL 6

// ---------------------------------------------------------------------------
// Batched GEMM: C[128][2048] = W[128][128] @ X[128][2048] + b
// Used for Q/K/V projections (6 ops) and the merge conv (2 ops).
// ---------------------------------------------------------------------------
struct GOp { const float* W; const float* B; const float* X; float* C; };
struct GOps { GOp op[6]; };

__global__ __launch_bounds__(256) void gemm128_kernel(GOps P) {
  const GOp g = P.op[blockIdx.z];
  const int bn = blockIdx.x * 64;
  const int bm = blockIdx.y * 64;
  __shared__ float Ws[32][65];   // [k][m], pad 65 -> conflict-free transpose store
  __shared__ float Xs[32][64];   // [k][n]
  const int t = threadIdx.x;
  const int tm = (t >> 4) << 2;
  const int tn = (t & 15) << 2;
  float acc[4][4] = {{0.f}};
  for (int k0 = 0; k0 < 128; k0 += 32) {
#pragma unroll
    for (int i = 0; i < 8; ++i) {
      int e = t + i * 256;  // 2048 elems
      Ws[e & 31][e >> 5] = g.W[(bm + (e >> 5)) * 128 + k0 + (e & 31)];
    }
#pragma unroll
    for (int i = 0; i < 2; ++i) {
      int e = t + i * 256;  // 512 float4
      int r = e >> 4, c4 = e & 15;
      *(float4*)&Xs[r][c4 * 4] = *(const float4*)&g.X[(size_t)(k0 + r) * NN + bn + c4 * 4];
    }
    __syncthreads();
#pragma unroll
    for (int kk = 0; kk < 32; ++kk) {
      float a[4];
      a[0] = Ws[kk][tm]; a[1] = Ws[kk][tm + 1]; a[2] = Ws[kk][tm + 2]; a[3] = Ws[kk][tm + 3];
      float4 b4 = *(const float4*)&Xs[kk][tn];
      float bb[4] = {b4.x, b4.y, b4.z, b4.w};
#pragma unroll
      for (int i = 0; i < 4; ++i)
#pragma unroll
        for (int j = 0; j < 4; ++j) acc[i][j] += a[i] * bb[j];
    }
    __syncthreads();
  }
#pragma unroll
  for (int i = 0; i < 4; ++i) {
    float bias = g.B[bm + tm + i];
    float4 r = make_float4(acc[i][0] + bias, acc[i][1] + bias, acc[i][2] + bias, acc[i][3] + bias);
    *(float4*)&g.C[(size_t)(bm + tm + i) * NN + bn + tn] = r;
  }
}

// ---------------------------------------------------------------------------
// Two-pass flash attention. Grid: (N/64 q-tiles, 4 heads, 2 descs).
// Channel layout: q[d,h,n] = Q[(d*NHEAD + h)*NN + n]  (reshape(b, DH, H, -1)).
// Block: 256 threads = 64 queries x 4 key-partitions; merge via LDS.
// ---------------------------------------------------------------------------
__global__ __launch_bounds__(256) void attn_kernel(
    const float* __restrict__ q0, const float* __restrict__ k0, const float* __restrict__ v0,
    const float* __restrict__ q1, const float* __restrict__ k1, const float* __restrict__ v1,
    float* __restrict__ m0, float* __restrict__ m1, int cross) {
  const int z = blockIdx.z;
  const int h = blockIdx.y;
  const int n0 = blockIdx.x * 64;
  const float* Q = z ? q1 : q0;
  const int s = cross ? (1 - z) : z;
  const float* K = s ? k1 : k0;
  const float* V = s ? v1 : v0;
  float* OM = z ? m1 : m0;

  const int t = threadIdx.x;
  const int ql = t & 63;
  const int part = t >> 6;

  __shared__ float Ks[DH][128];
  __shared__ float Vs[DH][128];
  __shared__ float red_m[256];
  __shared__ float red_l[256];
  __shared__ float red_o[4][64][DH + 1];
  __shared__ float mfin[64];

  const float scale = 0.17677669529663687f;  // 1/sqrt(32)
  float qreg[DH];
#pragma unroll
  for (int d = 0; d < DH; ++d)
    qreg[d] = Q[(size_t)(d * NHEAD + h) * NN + n0 + ql] * scale;

  // ---- pass 1: row max over this thread's key partition ----
  float mx = -1e30f;
  for (int kt = 0; kt < NN; kt += 128) {
    __syncthreads();
#pragma unroll
    for (int i = 0; i < 4; ++i) {
      int e = t + i * 256;  // 1024 float4
      int d = e >> 5, c4 = e & 31;
      *(float4*)&Ks[d][c4 * 4] = *(const float4*)&K[(size_t)(d * NHEAD + h) * NN + kt + c4 * 4];
    }
    __syncthreads();
#pragma unroll 2
    for (int j = 0; j < 32; j += 4) {
      const int jj = part * 32 + j;
      float s0 = 0.f, s1 = 0.f, s2 = 0.f, s3 = 0.f;
#pragma unroll
      for (int d = 0; d < DH; ++d) {
        float4 kv = *(const float4*)&Ks[d][jj];
        s0 += qreg[d] * kv.x; s1 += qreg[d] * kv.y;
        s2 += qreg[d] * kv.z; s3 += qreg[d] * kv.w;
      }
      mx = fmaxf(mx, fmaxf(fmaxf(s0, s1), fmaxf(s2, s3)));
    }
  }
  red_m[part * 64 + ql] = mx;
  __syncthreads();
  if (t < 64)
    mfin[ql] = fmaxf(fmaxf(red_m[ql], red_m[64 + ql]), fmaxf(red_m[128 + ql], red_m[192 + ql]));
  __syncthreads();
  const float gm = mfin[ql];

  // ---- pass 2: sum exp + PV accumulate ----
  float l = 0.f;
  float o[DH];
#pragma unroll
  for (int d = 0; d < DH; ++d) o[d] = 0.f;
  for (int kt = 0; kt < NN; kt += 128) {
    __syncthreads();
#pragma unroll
    for (int i = 0; i < 4; ++i) {
      int e = t + i * 256;
      int d = e >> 5, c4 = e & 31;
      *(float4*)&Ks[d][c4 * 4] = *(const float4*)&K[(size_t)(d * NHEAD + h) * NN + kt + c4 * 4];
      *(float4*)&Vs[d][c4 * 4] = *(const float4*)&V[(size_t)(d * NHEAD + h) * NN + kt + c4 * 4];
    }
    __syncthreads();
#pragma unroll 2
    for (int j = 0; j < 32; j += 4) {
      const int jj = part * 32 + j;
      float s0 = 0.f, s1 = 0.f, s2 = 0.f, s3 = 0.f;
#pragma unroll
      for (int d = 0; d < DH; ++d) {
        float4 kv = *(const float4*)&Ks[d][jj];
        s0 += qreg[d] * kv.x; s1 += qreg[d] * kv.y;
        s2 += qreg[d] * kv.z; s3 += qreg[d] * kv.w;
      }
      float p0 = __expf(s0 - gm), p1 = __expf(s1 - gm);
      float p2 = __expf(s2 - gm), p3 = __expf(s3 - gm);
      l += (p0 + p1) + (p2 + p3);
#pragma unroll
      for (int d = 0; d < DH; ++d) {
        float4 vv = *(const float4*)&Vs[d][jj];
        o[d] += p0 * vv.x + p1 * vv.y + p2 * vv.z + p3 * vv.w;
      }
    }
  }
  red_l[part * 64 + ql] = l;
#pragma unroll
  for (int d = 0; d < DH; ++d) red_o[part][ql][d] = o[d];
  __syncthreads();
  if (t < 64) {
    float lt = red_l[ql] + red_l[64 + ql] + red_l[128 + ql] + red_l[192 + ql];
    float inv = 1.0f / lt;
#pragma unroll
    for (int d = 0; d < DH; ++d) {
      float ov = red_o[0][ql][d] + red_o[1][ql][d] + red_o[2][ql][d] + red_o[3][ql][d];
      OM[(size_t)(d * NHEAD + h) * NN + n0 + ql] = ov * inv;
    }
  }
}

// ---------------------------------------------------------------------------
// MLP layer 1: H[256][2048] = W1[256][256] @ concat(X1[128], X2[128]) + b1
// ---------------------------------------------------------------------------
__global__ __launch_bounds__(256) void mlp1_kernel(
    const float* __restrict__ W, const float* __restrict__ Bv,
    const float* __restrict__ X1a, const float* __restrict__ X2a, float* __restrict__ Ca,
    const float* __restrict__ X1b, const float* __restrict__ X2b, float* __restrict__ Cb) {
  const float* X1 = blockIdx.z ? X1b : X1a;
  const float* X2 = blockIdx.z ? X2b : X2a;
  float* C = blockIdx.z ? Cb : Ca;
  const int bn = blockIdx.x * 64;
  const int bm = blockIdx.y * 64;
  __shared__ float Ws[32][65];
  __shared__ float Xs[32][64];
  const int t = threadIdx.x;
  const int tm = (t >> 4) << 2;
  const int tn = (t & 15) << 2;
  float acc[4][4] = {{0.f}};
  for (int k0 = 0; k0 < 256; k0 += 32) {
#pragma unroll
    for (int i = 0; i < 8; ++i) {
      int e = t + i * 256;
      Ws[e & 31][e >> 5] = W[(size_t)(bm + (e >> 5)) * 256 + k0 + (e & 31)];
    }
    const float* Xp = (k0 < 128) ? X1 : X2;
    const int kb = k0 & 127;
#pragma unroll
    for (int i = 0; i < 2; ++i) {
      int e = t + i * 256;
      int r = e >> 4, c4 = e & 15;
      *(float4*)&Xs[r][c4 * 4] = *(const float4*)&Xp[(size_t)(kb + r) * NN + bn + c4 * 4];
    }
    __syncthreads();
#pragma unroll
    for (int kk = 0; kk < 32; ++kk) {
      float a[4];
      a[0] = Ws[kk][tm]; a[1] = Ws[kk][tm + 1]; a[2] = Ws[kk][tm + 2]; a[3] = Ws[kk][tm + 3];
      float4 b4 = *(const float4*)&Xs[kk][tn];
      float bb[4] = {b4.x, b4.y, b4.z, b4.w};
#pragma unroll
      for (int i = 0; i < 4; ++i)
#pragma unroll
        for (int j = 0; j < 4; ++j) acc[i][j] += a[i] * bb[j];
    }
    __syncthreads();
  }
#pragma unroll
  for (int i = 0; i < 4; ++i) {
    float bias = Bv[bm + tm + i];
    float4 r = make_float4(acc[i][0] + bias, acc[i][1] + bias, acc[i][2] + bias, acc[i][3] + bias);
    *(float4*)&C[(size_t)(bm + tm + i) * NN + bn + tn] = r;
  }
}

// ---------------------------------------------------------------------------
// InstanceNorm stats: mean + rsqrt(var+eps) per channel (256 ch x 2 descs)
// ---------------------------------------------------------------------------
__global__ __launch_bounds__(256) void stats_kernel(
    const float* __restrict__ h0, const float* __restrict__ h1,
    float* __restrict__ s0, float* __restrict__ s1) {
  const float* Hp = blockIdx.y ? h1 : h0;
  float* st = blockIdx.y ? s1 : s0;
  const int c = blockIdx.x;
  const float* row = Hp + (size_t)c * NN;
  float s = 0.f, ss = 0.f;
  for (int i = threadIdx.x; i < NN; i += 256) {
    float v = row[i];
    s += v; ss += v * v;
  }
#pragma unroll
  for (int off = 32; off; off >>= 1) {
    s += __shfl_down(s, off);
    ss += __shfl_down(ss, off);
  }
  __shared__ float as[4], as2[4];
  const int w = threadIdx.x >> 6;
  if ((threadIdx.x & 63) == 0) { as[w] = s; as2[w] = ss; }
  __syncthreads();
  if (threadIdx.x == 0) {
    float S = as[0] + as[1] + as[2] + as[3];
    float SS = as2[0] + as2[1] + as2[2] + as2[3];
    float mean = S * (1.0f / NN);
    float var = fmaxf(SS * (1.0f / NN) - mean * mean, 0.f);
    st[c * 2] = mean;
    st[c * 2 + 1] = rsqrtf(var + 1e-5f);
  }
}

// ---------------------------------------------------------------------------
// MLP layer 2 + residual: D += W2[128][256] @ relu((H-mean)*rstd) + b2
// ---------------------------------------------------------------------------
__global__ __launch_bounds__(256) void mlp2_kernel(
    const float* __restrict__ W, const float* __restrict__ Bv,
    const float* __restrict__ Ha, const float* __restrict__ sa, float* __restrict__ Da,
    const float* __restrict__ Hb, const float* __restrict__ sb, float* __restrict__ Db) {
  const float* Hp = blockIdx.z ? Hb : Ha;
  const float* st = blockIdx.z ? sb : sa;
  float* Dp = blockIdx.z ? Db : Da;
  const int bn = blockIdx.x * 64;
  const int bm = blockIdx.y * 64;
  __shared__ float Ws[32][65];
  __shared__ float Xs[32][64];
  const int t = threadIdx.x;
  const int tm = (t >> 4) << 2;
  const int tn = (t & 15) << 2;
  float acc[4][4] = {{0.f}};
  for (int k0 = 0; k0 < 256; k0 += 32) {
#pragma unroll
    for (int i = 0; i < 8; ++i) {
      int e = t + i * 256;
      Ws[e & 31][e >> 5] = W[(size_t)(bm + (e >> 5)) * 256 + k0 + (e & 31)];
    }
#pragma unroll
    for (int i = 0; i < 2; ++i) {
      int e = t + i * 256;
      int r = e >> 4, c4 = e & 15;
      const int kc = k0 + r;
      float mean = st[kc * 2];
      float rstd = st[kc * 2 + 1];
      float4 v = *(const float4*)&Hp[(size_t)kc * NN + bn + c4 * 4];
      v.x = fmaxf((v.x - mean) * rstd, 0.f);
      v.y = fmaxf((v.y - mean) * rstd, 0.f);
      v.z = fmaxf((v.z - mean) * rstd, 0.f);
      v.w = fmaxf((v.w - mean) * rstd, 0.f);
      *(float4*)&Xs[r][c4 * 4] = v;
    }
    __syncthreads();
#pragma unroll
    for (int kk = 0; kk < 32; ++kk) {
      float a[4];
      a[0] = Ws[kk][tm]; a[1] = Ws[kk][tm + 1]; a[2] = Ws[kk][tm + 2]; a[3] = Ws[kk][tm + 3];
      float4 b4 = *(const float4*)&Xs[kk][tn];
      float bb[4] = {b4.x, b4.y, b4.z, b4.w};
#pragma unroll
      for (int i = 0; i < 4; ++i)
#pragma unroll
        for (int j = 0; j < 4; ++j) acc[i][j] += a[i] * bb[j];
    }
    __syncthreads();
  }
#pragma unroll
  for (int i = 0; i < 4; ++i) {
    float bias = Bv[bm + tm + i];
    float4* dst = (float4*)&Dp[(size_t)(bm + tm + i) * NN + bn + tn];
    float4 old = *dst;
    old.x += acc[i][0] + bias;
    old.y += acc[i][1] + bias;
    old.z += acc[i][2] + bias;
    old.w += acc[i][3] + bias;
    *dst = old;
  }
}

// ---------------------------------------------------------------------------
extern "C" void kernel_launch(void* const* d_in, const int* in_sizes, int n_in,
                              void* d_out, int out_size, void* d_ws, size_t ws_size,
                              hipStream_t stream) {
  const float* desc0 = (const float*)d_in[0];
  const float* desc1 = (const float*)d_in[1];
  const float* Wq = (const float*)d_in[2];
  const float* bq = (const float*)d_in[3];
  const float* Wk = (const float*)d_in[4];
  const float* bk = (const float*)d_in[5];
  const float* Wv = (const float*)d_in[6];
  const float* bv = (const float*)d_in[7];
  const float* Wm = (const float*)d_in[8];
  const float* bmv = (const float*)d_in[9];
  const float* W1 = (const float*)d_in[10];
  const float* b1 = (const float*)d_in[11];
  const float* W2 = (const float*)d_in[12];
  const float* b2 = (const float*)d_in[13];

  float* out0 = (float*)d_out;
  float* out1 = out0 + (size_t)DDIM * NN;
  float* ws = (float*)d_ws;
  const size_t S = (size_t)DDIM * NN;  // 262144
  float* q0 = ws + 0 * S;  float* q1 = ws + 1 * S;
  float* k0 = ws + 2 * S;  float* k1 = ws + 3 * S;
  float* v0 = ws + 4 * S;  float* v1 = ws + 5 * S;
  float* mg0 = ws + 6 * S; float* mg1 = ws + 7 * S;
  float* mm0 = ws + 8 * S; float* mm1 = ws + 9 * S;
  float* h0 = ws + 10 * S; float* h1 = ws + 12 * S;  // each 2*S
  float* s0 = ws + 14 * S; float* s1 = s0 + 512;

  (void)hipMemcpyAsync(out0, desc0, S * sizeof(float), hipMemcpyDeviceToDevice, stream);
  (void)hipMemcpyAsync(out1, desc1, S * sizeof(float), hipMemcpyDeviceToDevice, stream);

  for (int l = 0; l < NL; ++l) {
    const int cross = l & 1;
    const float* wq = Wq + (size_t)l * DDIM * DDIM;
    const float* wk = Wk + (size_t)l * DDIM * DDIM;
    const float* wv = Wv + (size_t)l * DDIM * DDIM;
    const float* wm = Wm + (size_t)l * DDIM * DDIM;
    const float* bqp = bq + (size_t)l * DDIM;
    const float* bkp = bk + (size_t)l * DDIM;
    const float* bvp = bv + (size_t)l * DDIM;
    const float* bmp = bmv + (size_t)l * DDIM;

    GOps Pq;
    Pq.op[0] = {wq, bqp, out0, q0};
    Pq.op[1] = {wq, bqp, out1, q1};
    Pq.op[2] = {wk, bkp, out0, k0};
    Pq.op[3] = {wk, bkp, out1, k1};
    Pq.op[4] = {wv, bvp, out0, v0};
    Pq.op[5] = {wv, bvp, out1, v1};
    gemm128_kernel<<<dim3(32, 2, 6), 256, 0, stream>>>(Pq);

    attn_kernel<<<dim3(32, 4, 2), 256, 0, stream>>>(q0, k0, v0, q1, k1, v1, mg0, mg1, cross);

    GOps Pm;
    Pm.op[0] = {wm, bmp, mg0, mm0};
    Pm.op[1] = {wm, bmp, mg1, mm1};
    Pm.op[2] = Pm.op[0]; Pm.op[3] = Pm.op[0]; Pm.op[4] = Pm.op[0]; Pm.op[5] = Pm.op[0];
    gemm128_kernel<<<dim3(32, 2, 2), 256, 0, stream>>>(Pm);

    mlp1_kernel<<<dim3(32, 4, 2), 256, 0, stream>>>(
        W1 + (size_t)l * 256 * 256, b1 + (size_t)l * 256, out0, mm0, h0, out1, mm1, h1);

    stats_kernel<<<dim3(256, 2), 256, 0, stream>>>(h0, h1, s0, s1);

    mlp2_kernel<<<dim3(32, 2, 2), 256, 0, stream>>>(
        W2 + (size_t)l * 128 * 256, b2 + (size_t)l * 128, h0, s0, out0, h1, s1, out1);
  }
}

// Round 2
// 1927.319 us; speedup vs baseline: 1.4340x; 1.4340x over previous
//
#include <hip/hip_runtime.h>

#define NN 2048      // sequence length
#define DDIM 128     // d_model
#define NHEAD 4
#define DH 32        // per-head dim
#define NL 6

// ---------------------------------------------------------------------------
// Batched GEMM: C[128][2048] = W[128][128] @ X[128][2048] + b
// Used for Q/K/V projections (6 ops) and the merge conv (2 ops).
// ---------------------------------------------------------------------------
struct GOp { const float* W; const float* B; const float* X; float* C; };
struct GOps { GOp op[6]; };

__global__ __launch_bounds__(256) void gemm128_kernel(GOps P) {
  const GOp g = P.op[blockIdx.z];
  const int bn = blockIdx.x * 64;
  const int bm = blockIdx.y * 64;
  __shared__ float Ws[32][65];   // [k][m], pad 65 -> conflict-free transpose store
  __shared__ float Xs[32][64];   // [k][n]
  const int t = threadIdx.x;
  const int tm = (t >> 4) << 2;
  const int tn = (t & 15) << 2;
  float acc[4][4] = {{0.f}};
  for (int k0 = 0; k0 < 128; k0 += 32) {
#pragma unroll
    for (int i = 0; i < 8; ++i) {
      int e = t + i * 256;  // 2048 elems
      Ws[e & 31][e >> 5] = g.W[(bm + (e >> 5)) * 128 + k0 + (e & 31)];
    }
#pragma unroll
    for (int i = 0; i < 2; ++i) {
      int e = t + i * 256;  // 512 float4
      int r = e >> 4, c4 = e & 15;
      *(float4*)&Xs[r][c4 * 4] = *(const float4*)&g.X[(size_t)(k0 + r) * NN + bn + c4 * 4];
    }
    __syncthreads();
#pragma unroll
    for (int kk = 0; kk < 32; ++kk) {
      float a[4];
      a[0] = Ws[kk][tm]; a[1] = Ws[kk][tm + 1]; a[2] = Ws[kk][tm + 2]; a[3] = Ws[kk][tm + 3];
      float4 b4 = *(const float4*)&Xs[kk][tn];
      float bb[4] = {b4.x, b4.y, b4.z, b4.w};
#pragma unroll
      for (int i = 0; i < 4; ++i)
#pragma unroll
        for (int j = 0; j < 4; ++j) acc[i][j] += a[i] * bb[j];
    }
    __syncthreads();
  }
#pragma unroll
  for (int i = 0; i < 4; ++i) {
    float bias = g.B[bm + tm + i];
    float4 r = make_float4(acc[i][0] + bias, acc[i][1] + bias, acc[i][2] + bias, acc[i][3] + bias);
    *(float4*)&g.C[(size_t)(bm + tm + i) * NN + bn + tn] = r;
  }
}

// ---------------------------------------------------------------------------
// Single-pass online-softmax attention, key-split across blocks.
// Grid: (32 q-tiles, 4 key-chunks of 512, 8 = desc*4+head). Block 256.
// Thread t: query ql = t&63, key-partition part = t>>6 (one wave each).
// Writes partial (m, l, O-unnormalized) per (z, chunk, q) to ws.
// ---------------------------------------------------------------------------
__global__ __launch_bounds__(256, 4) void attn_part_kernel(
    const float* __restrict__ q0, const float* __restrict__ k0, const float* __restrict__ v0,
    const float* __restrict__ q1, const float* __restrict__ k1, const float* __restrict__ v1,
    float* __restrict__ Pm, float* __restrict__ Pl, float* __restrict__ Po, int cross) {
  const int z = blockIdx.z;        // desc*4 + head
  const int desc = z >> 2;
  const int h = z & 3;
  const int chunk = blockIdx.y;    // 512 keys per chunk
  const int n0 = blockIdx.x * 64;  // query tile base
  const float* Q = desc ? q1 : q0;
  const int s = cross ? (1 - desc) : desc;
  const float* K = s ? k1 : k0;
  const float* V = s ? v1 : v0;

  const int t = threadIdx.x;
  const int ql = t & 63;
  const int part = t >> 6;

  // 9728 floats = 38912 B: tiles Ks[32][128]+Vs[32][128] = 8192 floats,
  // aliased afterwards by merge scratch redo[4][64][36] (9216) + m/l (512).
  __shared__ __align__(16) float smem[9728];
  float* Ks = smem;            // [d][128]
  float* Vs = smem + 4096;     // [d][128]

  const float scale = 0.17677669529663687f;  // 1/sqrt(32)
  float qreg[DH];
#pragma unroll
  for (int d = 0; d < DH; ++d)
    qreg[d] = Q[(size_t)(d * NHEAD + h) * NN + n0 + ql] * scale;

  float m = -1e30f, l = 0.f;
  float o[DH];
#pragma unroll
  for (int d = 0; d < DH; ++d) o[d] = 0.f;

  const int kbase = chunk * 512;
  for (int kt = 0; kt < 512; kt += 128) {
    __syncthreads();
#pragma unroll
    for (int i = 0; i < 4; ++i) {
      int e = t + i * 256;  // 1024 float4 per array
      int d = e >> 5, c4 = e & 31;
      *(float4*)&Ks[d * 128 + c4 * 4] =
          *(const float4*)&K[(size_t)(d * NHEAD + h) * NN + kbase + kt + c4 * 4];
      *(float4*)&Vs[d * 128 + c4 * 4] =
          *(const float4*)&V[(size_t)(d * NHEAD + h) * NN + kbase + kt + c4 * 4];
    }
    __syncthreads();

    const int jj = part * 32;
    float sreg[32];
#pragma unroll
    for (int jg = 0; jg < 32; jg += 4) {
      float a0 = 0.f, a1 = 0.f, a2 = 0.f, a3 = 0.f;
#pragma unroll
      for (int d = 0; d < DH; ++d) {
        float4 kv = *(const float4*)&Ks[d * 128 + jj + jg];
        a0 += qreg[d] * kv.x; a1 += qreg[d] * kv.y;
        a2 += qreg[d] * kv.z; a3 += qreg[d] * kv.w;
      }
      sreg[jg] = a0; sreg[jg + 1] = a1; sreg[jg + 2] = a2; sreg[jg + 3] = a3;
    }
    float tm = sreg[0];
#pragma unroll
    for (int j = 1; j < 32; ++j) tm = fmaxf(tm, sreg[j]);
    float mn = fmaxf(m, tm);
    float sc = __expf(m - mn);   // first iter: exp(-huge) -> 0
    m = mn;
    l *= sc;
#pragma unroll
    for (int d = 0; d < DH; ++d) o[d] *= sc;
#pragma unroll
    for (int j = 0; j < 32; ++j) {
      float p = __expf(sreg[j] - m);
      sreg[j] = p;
      l += p;
    }
#pragma unroll
    for (int jg = 0; jg < 32; jg += 4) {
      float p0 = sreg[jg], p1 = sreg[jg + 1], p2 = sreg[jg + 2], p3 = sreg[jg + 3];
#pragma unroll
      for (int d = 0; d < DH; ++d) {
        float4 vv = *(const float4*)&Vs[d * 128 + jj + jg];
        o[d] += p0 * vv.x + p1 * vv.y + p2 * vv.z + p3 * vv.w;
      }
    }
  }

  // ---- merge 4 partitions (one per wave) via aliased LDS ----
  __syncthreads();
  float* redo = smem;               // [part][ql][36] -> 9216 floats
  float* red_m = smem + 9216;       // [part*64 + ql]
  float* red_l = smem + 9472;
  red_m[part * 64 + ql] = m;
  red_l[part * 64 + ql] = l;
#pragma unroll
  for (int d = 0; d < DH; d += 4) {
    float4 v4 = make_float4(o[d], o[d + 1], o[d + 2], o[d + 3]);
    *(float4*)&redo[part * 2304 + ql * 36 + d] = v4;
  }
  __syncthreads();
  if (t < 64) {
    float m0v = red_m[ql], m1v = red_m[64 + ql], m2v = red_m[128 + ql], m3v = red_m[192 + ql];
    float M = fmaxf(fmaxf(m0v, m1v), fmaxf(m2v, m3v));
    float w0 = __expf(m0v - M), w1 = __expf(m1v - M);
    float w2 = __expf(m2v - M), w3 = __expf(m3v - M);
    float L = w0 * red_l[ql] + w1 * red_l[64 + ql] + w2 * red_l[128 + ql] + w3 * red_l[192 + ql];
    const size_t pidx = (size_t)(z * 4 + chunk) * 2048 + n0 + ql;
    Pm[pidx] = M;
    Pl[pidx] = L;
#pragma unroll
    for (int d = 0; d < DH; ++d) {
      float O = w0 * redo[ql * 36 + d] + w1 * redo[2304 + ql * 36 + d] +
                w2 * redo[4608 + ql * 36 + d] + w3 * redo[6912 + ql * 36 + d];
      Po[((size_t)(z * 4 + chunk) * 32 + d) * 2048 + n0 + ql] = O;
    }
  }
}

// ---------------------------------------------------------------------------
// Merge 4 key-chunk partials per query -> normalized message.
// Grid: (8, 8): x covers 2048 queries (256/block), y = desc*4+head.
// ---------------------------------------------------------------------------
__global__ __launch_bounds__(256) void attn_merge_kernel(
    const float* __restrict__ Pm, const float* __restrict__ Pl, const float* __restrict__ Po,
    float* __restrict__ mg0, float* __restrict__ mg1) {
  const int z = blockIdx.y;
  const int desc = z >> 2;
  const int h = z & 3;
  const int q = blockIdx.x * 256 + threadIdx.x;
  const size_t b = (size_t)z * 4 * 2048 + q;
  float m0v = Pm[b], m1v = Pm[b + 2048], m2v = Pm[b + 4096], m3v = Pm[b + 6144];
  float M = fmaxf(fmaxf(m0v, m1v), fmaxf(m2v, m3v));
  float w0 = __expf(m0v - M), w1 = __expf(m1v - M);
  float w2 = __expf(m2v - M), w3 = __expf(m3v - M);
  float L = w0 * Pl[b] + w1 * Pl[b + 2048] + w2 * Pl[b + 4096] + w3 * Pl[b + 6144];
  float inv = 1.0f / L;
  float* OM = desc ? mg1 : mg0;
#pragma unroll
  for (int d = 0; d < DH; ++d) {
    const size_t ob = ((size_t)z * 4 * 32 + d) * 2048 + q;
    float acc = w0 * Po[ob] + w1 * Po[ob + 32 * 2048] +
                w2 * Po[ob + 64 * 2048] + w3 * Po[ob + 96 * 2048];
    OM[(size_t)(d * NHEAD + h) * NN + q] = acc * inv;
  }
}

// ---------------------------------------------------------------------------
// MLP layer 1: H[256][2048] = W1[256][256] @ concat(X1[128], X2[128]) + b1
// ---------------------------------------------------------------------------
__global__ __launch_bounds__(256) void mlp1_kernel(
    const float* __restrict__ W, const float* __restrict__ Bv,
    const float* __restrict__ X1a, const float* __restrict__ X2a, float* __restrict__ Ca,
    const float* __restrict__ X1b, const float* __restrict__ X2b, float* __restrict__ Cb) {
  const float* X1 = blockIdx.z ? X1b : X1a;
  const float* X2 = blockIdx.z ? X2b : X2a;
  float* C = blockIdx.z ? Cb : Ca;
  const int bn = blockIdx.x * 64;
  const int bm = blockIdx.y * 64;
  __shared__ float Ws[32][65];
  __shared__ float Xs[32][64];
  const int t = threadIdx.x;
  const int tm = (t >> 4) << 2;
  const int tn = (t & 15) << 2;
  float acc[4][4] = {{0.f}};
  for (int k0 = 0; k0 < 256; k0 += 32) {
#pragma unroll
    for (int i = 0; i < 8; ++i) {
      int e = t + i * 256;
      Ws[e & 31][e >> 5] = W[(size_t)(bm + (e >> 5)) * 256 + k0 + (e & 31)];
    }
    const float* Xp = (k0 < 128) ? X1 : X2;
    const int kb = k0 & 127;
#pragma unroll
    for (int i = 0; i < 2; ++i) {
      int e = t + i * 256;
      int r = e >> 4, c4 = e & 15;
      *(float4*)&Xs[r][c4 * 4] = *(const float4*)&Xp[(size_t)(kb + r) * NN + bn + c4 * 4];
    }
    __syncthreads();
#pragma unroll
    for (int kk = 0; kk < 32; ++kk) {
      float a[4];
      a[0] = Ws[kk][tm]; a[1] = Ws[kk][tm + 1]; a[2] = Ws[kk][tm + 2]; a[3] = Ws[kk][tm + 3];
      float4 b4 = *(const float4*)&Xs[kk][tn];
      float bb[4] = {b4.x, b4.y, b4.z, b4.w};
#pragma unroll
      for (int i = 0; i < 4; ++i)
#pragma unroll
        for (int j = 0; j < 4; ++j) acc[i][j] += a[i] * bb[j];
    }
    __syncthreads();
  }
#pragma unroll
  for (int i = 0; i < 4; ++i) {
    float bias = Bv[bm + tm + i];
    float4 r = make_float4(acc[i][0] + bias, acc[i][1] + bias, acc[i][2] + bias, acc[i][3] + bias);
    *(float4*)&C[(size_t)(bm + tm + i) * NN + bn + tn] = r;
  }
}

// ---------------------------------------------------------------------------
// InstanceNorm stats: mean + rsqrt(var+eps) per channel (256 ch x 2 descs)
// ---------------------------------------------------------------------------
__global__ __launch_bounds__(256) void stats_kernel(
    const float* __restrict__ h0, const float* __restrict__ h1,
    float* __restrict__ s0, float* __restrict__ s1) {
  const float* Hp = blockIdx.y ? h1 : h0;
  float* st = blockIdx.y ? s1 : s0;
  const int c = blockIdx.x;
  const float* row = Hp + (size_t)c * NN;
  float s = 0.f, ss = 0.f;
  for (int i = threadIdx.x; i < NN; i += 256) {
    float v = row[i];
    s += v; ss += v * v;
  }
#pragma unroll
  for (int off = 32; off; off >>= 1) {
    s += __shfl_down(s, off);
    ss += __shfl_down(ss, off);
  }
  __shared__ float as[4], as2[4];
  const int w = threadIdx.x >> 6;
  if ((threadIdx.x & 63) == 0) { as[w] = s; as2[w] = ss; }
  __syncthreads();
  if (threadIdx.x == 0) {
    float S = as[0] + as[1] + as[2] + as[3];
    float SS = as2[0] + as2[1] + as2[2] + as2[3];
    float mean = S * (1.0f / NN);
    float var = fmaxf(SS * (1.0f / NN) - mean * mean, 0.f);
    st[c * 2] = mean;
    st[c * 2 + 1] = rsqrtf(var + 1e-5f);
  }
}

// ---------------------------------------------------------------------------
// MLP layer 2 + residual: D += W2[128][256] @ relu((H-mean)*rstd) + b2
// ---------------------------------------------------------------------------
__global__ __launch_bounds__(256) void mlp2_kernel(
    const float* __restrict__ W, const float* __restrict__ Bv,
    const float* __restrict__ Ha, const float* __restrict__ sa, float* __restrict__ Da,
    const float* __restrict__ Hb, const float* __restrict__ sb, float* __restrict__ Db) {
  const float* Hp = blockIdx.z ? Hb : Ha;
  const float* st = blockIdx.z ? sb : sa;
  float* Dp = blockIdx.z ? Db : Da;
  const int bn = blockIdx.x * 64;
  const int bm = blockIdx.y * 64;
  __shared__ float Ws[32][65];
  __shared__ float Xs[32][64];
  const int t = threadIdx.x;
  const int tm = (t >> 4) << 2;
  const int tn = (t & 15) << 2;
  float acc[4][4] = {{0.f}};
  for (int k0 = 0; k0 < 256; k0 += 32) {
#pragma unroll
    for (int i = 0; i < 8; ++i) {
      int e = t + i * 256;
      Ws[e & 31][e >> 5] = W[(size_t)(bm + (e >> 5)) * 256 + k0 + (e & 31)];
    }
#pragma unroll
    for (int i = 0; i < 2; ++i) {
      int e = t + i * 256;
      int r = e >> 4, c4 = e & 15;
      const int kc = k0 + r;
      float mean = st[kc * 2];
      float rstd = st[kc * 2 + 1];
      float4 v = *(const float4*)&Hp[(size_t)kc * NN + bn + c4 * 4];
      v.x = fmaxf((v.x - mean) * rstd, 0.f);
      v.y = fmaxf((v.y - mean) * rstd, 0.f);
      v.z = fmaxf((v.z - mean) * rstd, 0.f);
      v.w = fmaxf((v.w - mean) * rstd, 0.f);
      *(float4*)&Xs[r][c4 * 4] = v;
    }
    __syncthreads();
#pragma unroll
    for (int kk = 0; kk < 32; ++kk) {
      float a[4];
      a[0] = Ws[kk][tm]; a[1] = Ws[kk][tm + 1]; a[2] = Ws[kk][tm + 2]; a[3] = Ws[kk][tm + 3];
      float4 b4 = *(const float4*)&Xs[kk][tn];
      float bb[4] = {b4.x, b4.y, b4.z, b4.w};
#pragma unroll
      for (int i = 0; i < 4; ++i)
#pragma unroll
        for (int j = 0; j < 4; ++j) acc[i][j] += a[i] * bb[j];
    }
    __syncthreads();
  }
#pragma unroll
  for (int i = 0; i < 4; ++i) {
    float bias = Bv[bm + tm + i];
    float4* dst = (float4*)&Dp[(size_t)(bm + tm + i) * NN + bn + tn];
    float4 old = *dst;
    old.x += acc[i][0] + bias;
    old.y += acc[i][1] + bias;
    old.z += acc[i][2] + bias;
    old.w += acc[i][3] + bias;
    *dst = old;
  }
}

// ---------------------------------------------------------------------------
extern "C" void kernel_launch(void* const* d_in, const int* in_sizes, int n_in,
                              void* d_out, int out_size, void* d_ws, size_t ws_size,
                              hipStream_t stream) {
  const float* desc0 = (const float*)d_in[0];
  const float* desc1 = (const float*)d_in[1];
  const float* Wq = (const float*)d_in[2];
  const float* bq = (const float*)d_in[3];
  const float* Wk = (const float*)d_in[4];
  const float* bk = (const float*)d_in[5];
  const float* Wv = (const float*)d_in[6];
  const float* bv = (const float*)d_in[7];
  const float* Wm = (const float*)d_in[8];
  const float* bmv = (const float*)d_in[9];
  const float* W1 = (const float*)d_in[10];
  const float* b1 = (const float*)d_in[11];
  const float* W2 = (const float*)d_in[12];
  const float* b2 = (const float*)d_in[13];

  float* out0 = (float*)d_out;
  float* out1 = out0 + (size_t)DDIM * NN;
  float* ws = (float*)d_ws;
  const size_t S = (size_t)DDIM * NN;  // 262144
  float* q0 = ws + 0 * S;  float* q1 = ws + 1 * S;
  float* k0 = ws + 2 * S;  float* k1 = ws + 3 * S;
  float* v0 = ws + 4 * S;  float* v1 = ws + 5 * S;
  float* mg0 = ws + 6 * S; float* mg1 = ws + 7 * S;
  float* mm0 = ws + 8 * S; float* mm1 = ws + 9 * S;
  float* h0 = ws + 10 * S; float* h1 = ws + 12 * S;  // each 2*S
  float* s0 = ws + 14 * S; float* s1 = s0 + 512;
  float* Pm = ws + 14 * S + 1024;          // 8*4*2048 = 65536
  float* Pl = Pm + 65536;                  // 65536
  float* Po = Pl + 65536;                  // 8*4*32*2048 = 2097152

  (void)hipMemcpyAsync(out0, desc0, S * sizeof(float), hipMemcpyDeviceToDevice, stream);
  (void)hipMemcpyAsync(out1, desc1, S * sizeof(float), hipMemcpyDeviceToDevice, stream);

  for (int l = 0; l < NL; ++l) {
    const int cross = l & 1;
    const float* wq = Wq + (size_t)l * DDIM * DDIM;
    const float* wk = Wk + (size_t)l * DDIM * DDIM;
    const float* wv = Wv + (size_t)l * DDIM * DDIM;
    const float* wm = Wm + (size_t)l * DDIM * DDIM;
    const float* bqp = bq + (size_t)l * DDIM;
    const float* bkp = bk + (size_t)l * DDIM;
    const float* bvp = bv + (size_t)l * DDIM;
    const float* bmp = bmv + (size_t)l * DDIM;

    GOps Pq;
    Pq.op[0] = {wq, bqp, out0, q0};
    Pq.op[1] = {wq, bqp, out1, q1};
    Pq.op[2] = {wk, bkp, out0, k0};
    Pq.op[3] = {wk, bkp, out1, k1};
    Pq.op[4] = {wv, bvp, out0, v0};
    Pq.op[5] = {wv, bvp, out1, v1};
    gemm128_kernel<<<dim3(32, 2, 6), 256, 0, stream>>>(Pq);

    attn_part_kernel<<<dim3(32, 4, 8), 256, 0, stream>>>(q0, k0, v0, q1, k1, v1, Pm, Pl, Po, cross);
    attn_merge_kernel<<<dim3(8, 8), 256, 0, stream>>>(Pm, Pl, Po, mg0, mg1);

    GOps Pmm;
    Pmm.op[0] = {wm, bmp, mg0, mm0};
    Pmm.op[1] = {wm, bmp, mg1, mm1};
    Pmm.op[2] = Pmm.op[0]; Pmm.op[3] = Pmm.op[0]; Pmm.op[4] = Pmm.op[0]; Pmm.op[5] = Pmm.op[0];
    gemm128_kernel<<<dim3(32, 2, 2), 256, 0, stream>>>(Pmm);

    mlp1_kernel<<<dim3(32, 4, 2), 256, 0, stream>>>(
        W1 + (size_t)l * 256 * 256, b1 + (size_t)l * 256, out0, mm0, h0, out1, mm1, h1);

    stats_kernel<<<dim3(256, 2), 256, 0, stream>>>(h0, h1, s0, s1);

    mlp2_kernel<<<dim3(32, 2, 2), 256, 0, stream>>>(
        W2 + (size_t)l * 128 * 256, b2 + (size_t)l * 128, h0, s0, out0, h1, s1, out1);
  }
}

// Round 3
// 809.575 us; speedup vs baseline: 3.4139x; 2.3807x over previous
//
#include <hip/hip_runtime.h>

#define NN 2048      // sequence length
#define DDIM 128     // d_model
#define NHEAD 4
#define DH 32        // per-head dim
#define NL 6

typedef __attribute__((ext_vector_type(8))) __bf16 bf16x8;
typedef __attribute__((ext_vector_type(4))) float f32x4;

__device__ __forceinline__ unsigned int f2bf(float x) {
  unsigned int u = __float_as_uint(x);
  u += 0x7fff + ((u >> 16) & 1);   // RNE
  return u >> 16;
}
__device__ __forceinline__ unsigned int pk2(float a, float b) {
  return f2bf(a) | (f2bf(b) << 16);
}

// ---------------------------------------------------------------------------
// Batched fp32 GEMM: C[128][2048] = W[128][128] @ X[128][2048] + b  (merge conv)
// ---------------------------------------------------------------------------
struct GOp { const float* W; const float* B; const float* X; float* C; };
struct GOps { GOp op[6]; };

__global__ __launch_bounds__(256) void gemm128_kernel(GOps P) {
  const GOp g = P.op[blockIdx.z];
  const int bn = blockIdx.x * 64;
  const int bm = blockIdx.y * 64;
  __shared__ float Ws[32][65];
  __shared__ float Xs[32][64];
  const int t = threadIdx.x;
  const int tm = (t >> 4) << 2;
  const int tn = (t & 15) << 2;
  float acc[4][4] = {{0.f}};
  for (int k0 = 0; k0 < 128; k0 += 32) {
#pragma unroll
    for (int i = 0; i < 8; ++i) {
      int e = t + i * 256;
      Ws[e & 31][e >> 5] = g.W[(bm + (e >> 5)) * 128 + k0 + (e & 31)];
    }
#pragma unroll
    for (int i = 0; i < 2; ++i) {
      int e = t + i * 256;
      int r = e >> 4, c4 = e & 15;
      *(float4*)&Xs[r][c4 * 4] = *(const float4*)&g.X[(size_t)(k0 + r) * NN + bn + c4 * 4];
    }
    __syncthreads();
#pragma unroll
    for (int kk = 0; kk < 32; ++kk) {
      float a[4];
      a[0] = Ws[kk][tm]; a[1] = Ws[kk][tm + 1]; a[2] = Ws[kk][tm + 2]; a[3] = Ws[kk][tm + 3];
      float4 b4 = *(const float4*)&Xs[kk][tn];
      float bb[4] = {b4.x, b4.y, b4.z, b4.w};
#pragma unroll
      for (int i = 0; i < 4; ++i)
#pragma unroll
        for (int j = 0; j < 4; ++j) acc[i][j] += a[i] * bb[j];
    }
    __syncthreads();
  }
#pragma unroll
  for (int i = 0; i < 4; ++i) {
    float bias = g.B[bm + tm + i];
    float4 r = make_float4(acc[i][0] + bias, acc[i][1] + bias, acc[i][2] + bias, acc[i][3] + bias);
    *(float4*)&g.C[(size_t)(bm + tm + i) * NN + bn + tn] = r;
  }
}

// ---------------------------------------------------------------------------
// QKV GEMM -> bf16 outputs in attention-friendly layouts.
// mode 0 (Q): scaled by 1/sqrt(DH), layout [h][d][n]  (plane h*32+d)
// mode 1 (K): layout [h][n][d]   (pre-transposed for MFMA A-frags)
// mode 2 (V): layout [h][d][n]
// Channel c of the conv output maps to (d = c>>2, h = c&3)  [reshape(DH,H)]
// ---------------------------------------------------------------------------
struct QOp { const float* W; const float* B; const float* X; unsigned short* C; int mode; };
struct QOps { QOp op[6]; };

__global__ __launch_bounds__(256) void qkv_gemm_kernel(QOps P) {
  const QOp g = P.op[blockIdx.z];
  const int bn = blockIdx.x * 64;
  const int bm = blockIdx.y * 64;
  __shared__ float Ws[32][65];
  __shared__ float Xs[32][64];
  const int t = threadIdx.x;
  const int tm = (t >> 4) << 2;
  const int tn = (t & 15) << 2;
  float acc[4][4] = {{0.f}};
  for (int k0 = 0; k0 < 128; k0 += 32) {
#pragma unroll
    for (int i = 0; i < 8; ++i) {
      int e = t + i * 256;
      Ws[e & 31][e >> 5] = g.W[(bm + (e >> 5)) * 128 + k0 + (e & 31)];
    }
#pragma unroll
    for (int i = 0; i < 2; ++i) {
      int e = t + i * 256;
      int r = e >> 4, c4 = e & 15;
      *(float4*)&Xs[r][c4 * 4] = *(const float4*)&g.X[(size_t)(k0 + r) * NN + bn + c4 * 4];
    }
    __syncthreads();
#pragma unroll
    for (int kk = 0; kk < 32; ++kk) {
      float a[4];
      a[0] = Ws[kk][tm]; a[1] = Ws[kk][tm + 1]; a[2] = Ws[kk][tm + 2]; a[3] = Ws[kk][tm + 3];
      float4 b4 = *(const float4*)&Xs[kk][tn];
      float bb[4] = {b4.x, b4.y, b4.z, b4.w};
#pragma unroll
      for (int i = 0; i < 4; ++i)
#pragma unroll
        for (int j = 0; j < 4; ++j) acc[i][j] += a[i] * bb[j];
    }
    __syncthreads();
  }
  const float sc = (g.mode == 0) ? 0.17677669529663687f : 1.0f;
#pragma unroll
  for (int i = 0; i < 4; ++i) {
    const int c = bm + tm + i;
    const int d = c >> 2, hh = c & 3;
    const float bias = g.B[c];
    float v0 = (acc[i][0] + bias) * sc, v1 = (acc[i][1] + bias) * sc;
    float v2 = (acc[i][2] + bias) * sc, v3 = (acc[i][3] + bias) * sc;
    if (g.mode != 1) {
      uint2 w = { pk2(v0, v1), pk2(v2, v3) };
      *(uint2*)&g.C[(size_t)(hh * 32 + d) * 2048 + bn + tn] = w;
    } else {
      const int n = bn + tn;
      g.C[((size_t)hh * 2048 + n) * 32 + d]     = (unsigned short)f2bf(v0);
      g.C[((size_t)hh * 2048 + n + 1) * 32 + d] = (unsigned short)f2bf(v1);
      g.C[((size_t)hh * 2048 + n + 2) * 32 + d] = (unsigned short)f2bf(v2);
      g.C[((size_t)hh * 2048 + n + 3) * 32 + d] = (unsigned short)f2bf(v3);
    }
  }
}

// ---------------------------------------------------------------------------
// MFMA flash attention (bf16), online softmax, key-split across blocks.
// Grid: (16 q-tiles of 128, 4 key-chunks of 512, 8 = desc*4+head). Block 256.
// Each wave owns 32 queries (2 groups of 16). Computes S^T = K^T(A) x Q(B):
//   C tile: row = key = quad*4+reg, col = q = lane&15  -> softmax reductions
//   are in-lane over regs + shfl_xor(16,32) across quads.
// P^T re-enters PV as B-frag via per-wave LDS round trip.
// O[d][q] = V(A) x P^T(B), acc rows = d, cols = q.
// ---------------------------------------------------------------------------
__global__ __launch_bounds__(256) void attn_mfma_kernel(
    const unsigned short* __restrict__ Qb0, const unsigned short* __restrict__ Kt0,
    const unsigned short* __restrict__ Vb0, const unsigned short* __restrict__ Qb1,
    const unsigned short* __restrict__ Kt1, const unsigned short* __restrict__ Vb1,
    float* __restrict__ Pm, float* __restrict__ Pl, float* __restrict__ Po, int cross) {
  const int z = blockIdx.z, desc = z >> 2, h = z & 3;
  const int cy = blockIdx.y;                 // 512-key chunk
  const int t = threadIdx.x;
  const int wid = t >> 6, lane = t & 63;
  const int col = lane & 15, Qd = lane >> 4;
  const int q0w = blockIdx.x * 128 + wid * 32;

  const unsigned short* Qb = desc ? Qb1 : Qb0;
  const int s = cross ? (1 - desc) : desc;
  const unsigned short* Kt = s ? Kt1 : Kt0;
  const unsigned short* Vb = s ? Vb1 : Vb0;

  // LDS: Kt tile [64 keys][40 (32 d + pad)], V tile [32 d][72 (64 keys + pad)],
  // per-wave P^T scratch [16 q][40 (32 k + pad)]. All frag reads 16B-aligned,
  // bank aliasing <= 2-way (free).
  __shared__ __align__(16) unsigned short SM[7424];
  unsigned short* KtL = SM;               // 2560
  unsigned short* VL = SM + 2560;         // 2304
  unsigned short* PL = SM + 4864 + wid * 640;  // 640 per wave

  // Q B-frags: B[k=d=Qd*8+j][n=q=col], once per block
  bf16x8 bq[2];
#pragma unroll
  for (int g = 0; g < 2; ++g) {
    union { unsigned short u[8]; bf16x8 v; } tmp;
#pragma unroll
    for (int j = 0; j < 8; ++j)
      tmp.u[j] = Qb[(size_t)(h * 32 + Qd * 8 + j) * 2048 + q0w + g * 16 + col];
    bq[g] = tmp.v;
  }

  f32x4 o[2][2];
#pragma unroll
  for (int g = 0; g < 2; ++g)
#pragma unroll
    for (int h2 = 0; h2 < 2; ++h2) o[g][h2] = (f32x4){0.f, 0.f, 0.f, 0.f};
  float m[2] = {-1e30f, -1e30f}, l[2] = {0.f, 0.f};

  const int kbase = cy * 512;
  for (int kc = 0; kc < 512; kc += 64) {
    __syncthreads();
    {
      const int key = t >> 2, d8 = (t & 3) * 8;
      *(uint4*)&KtL[key * 40 + d8] =
          *(const uint4*)&Kt[((size_t)h * 2048 + kbase + kc + key) * 32 + d8];
      const int dv = t >> 3, c8 = (t & 7) * 8;
      *(uint4*)&VL[dv * 72 + c8] =
          *(const uint4*)&Vb[(size_t)(h * 32 + dv) * 2048 + kbase + kc + c8];
    }
    __syncthreads();
#pragma unroll
    for (int sub = 0; sub < 2; ++sub) {
      // K^T A-frags: A[m=key=col][k=d=Qd*8+j], two 16-key tiles
      bf16x8 aK0 = *(const bf16x8*)&KtL[(sub * 32 + col) * 40 + Qd * 8];
      bf16x8 aK1 = *(const bf16x8*)&KtL[(sub * 32 + 16 + col) * 40 + Qd * 8];
      // V A-frags: A[m=d=half*16+col][k=key=Qd*8+j]
      bf16x8 av0 = *(const bf16x8*)&VL[col * 72 + sub * 32 + Qd * 8];
      bf16x8 av1 = *(const bf16x8*)&VL[(16 + col) * 72 + sub * 32 + Qd * 8];
#pragma unroll
      for (int g = 0; g < 2; ++g) {
        f32x4 zacc = {0.f, 0.f, 0.f, 0.f};
        f32x4 s0 = __builtin_amdgcn_mfma_f32_16x16x32_bf16(aK0, bq[g], zacc, 0, 0, 0);
        f32x4 s1 = __builtin_amdgcn_mfma_f32_16x16x32_bf16(aK1, bq[g], zacc, 0, 0, 0);
        float cm = fmaxf(fmaxf(fmaxf(s0[0], s0[1]), fmaxf(s0[2], s0[3])),
                         fmaxf(fmaxf(s1[0], s1[1]), fmaxf(s1[2], s1[3])));
        cm = fmaxf(cm, __shfl_xor(cm, 16));
        cm = fmaxf(cm, __shfl_xor(cm, 32));
        const float mn = fmaxf(m[g], cm);
        const float alpha = __expf(m[g] - mn);
        m[g] = mn;
        float p00 = __expf(s0[0] - mn), p01 = __expf(s0[1] - mn);
        float p02 = __expf(s0[2] - mn), p03 = __expf(s0[3] - mn);
        float p10 = __expf(s1[0] - mn), p11 = __expf(s1[1] - mn);
        float p12 = __expf(s1[2] - mn), p13 = __expf(s1[3] - mn);
        float us = (p00 + p01) + (p02 + p03) + (p10 + p11) + (p12 + p13);
        us += __shfl_xor(us, 16);
        us += __shfl_xor(us, 32);
        l[g] = l[g] * alpha + us;
        // P^T -> per-wave LDS [q=col][k], rows of 40 (80B) for 16B-aligned reads
        uint2 w0 = { pk2(p00, p01), pk2(p02, p03) };
        uint2 w1 = { pk2(p10, p11), pk2(p12, p13) };
        *(uint2*)&PL[col * 40 + Qd * 4] = w0;
        *(uint2*)&PL[col * 40 + 16 + Qd * 4] = w1;
        __threadfence_block();
        bf16x8 pb = *(const bf16x8*)&PL[col * 40 + Qd * 8];  // B[k=Qd*8+j][n=col]
        o[g][0] = o[g][0] * alpha;
        o[g][1] = o[g][1] * alpha;
        o[g][0] = __builtin_amdgcn_mfma_f32_16x16x32_bf16(av0, pb, o[g][0], 0, 0, 0);
        o[g][1] = __builtin_amdgcn_mfma_f32_16x16x32_bf16(av1, pb, o[g][1], 0, 0, 0);
        __threadfence_block();
      }
    }
  }

  // partials: m, l per query (quad 0 lanes), unnormalized O
#pragma unroll
  for (int g = 0; g < 2; ++g) {
    const int q = q0w + g * 16 + col;
    if (Qd == 0) {
      const size_t pidx = (size_t)(z * 4 + cy) * 2048 + q;
      Pm[pidx] = m[g];
      Pl[pidx] = l[g];
    }
#pragma unroll
    for (int h2 = 0; h2 < 2; ++h2)
#pragma unroll
      for (int r = 0; r < 4; ++r) {
        const int d = h2 * 16 + Qd * 4 + r;
        Po[((size_t)(z * 4 + cy) * 32 + d) * 2048 + q] = o[g][h2][r];
      }
  }
}

// ---------------------------------------------------------------------------
// Merge 4 key-chunk partials per query -> normalized message (fp32 layout
// [d*NHEAD+h][n] consumed by the merge GEMM).
// ---------------------------------------------------------------------------
__global__ __launch_bounds__(256) void attn_merge_kernel(
    const float* __restrict__ Pm, const float* __restrict__ Pl, const float* __restrict__ Po,
    float* __restrict__ mg0, float* __restrict__ mg1) {
  const int z = blockIdx.y;
  const int desc = z >> 2;
  const int h = z & 3;
  const int q = blockIdx.x * 256 + threadIdx.x;
  const size_t b = (size_t)z * 4 * 2048 + q;
  float m0v = Pm[b], m1v = Pm[b + 2048], m2v = Pm[b + 4096], m3v = Pm[b + 6144];
  float M = fmaxf(fmaxf(m0v, m1v), fmaxf(m2v, m3v));
  float w0 = __expf(m0v - M), w1 = __expf(m1v - M);
  float w2 = __expf(m2v - M), w3 = __expf(m3v - M);
  float L = w0 * Pl[b] + w1 * Pl[b + 2048] + w2 * Pl[b + 4096] + w3 * Pl[b + 6144];
  float inv = 1.0f / L;
  float* OM = desc ? mg1 : mg0;
#pragma unroll
  for (int d = 0; d < DH; ++d) {
    const size_t ob = ((size_t)z * 4 * 32 + d) * 2048 + q;
    float acc = w0 * Po[ob] + w1 * Po[ob + 32 * 2048] +
                w2 * Po[ob + 64 * 2048] + w3 * Po[ob + 96 * 2048];
    OM[(size_t)(d * NHEAD + h) * NN + q] = acc * inv;
  }
}

// ---------------------------------------------------------------------------
// MLP layer 1: H[256][2048] = W1[256][256] @ concat(X1[128], X2[128]) + b1
// ---------------------------------------------------------------------------
__global__ __launch_bounds__(256) void mlp1_kernel(
    const float* __restrict__ W, const float* __restrict__ Bv,
    const float* __restrict__ X1a, const float* __restrict__ X2a, float* __restrict__ Ca,
    const float* __restrict__ X1b, const float* __restrict__ X2b, float* __restrict__ Cb) {
  const float* X1 = blockIdx.z ? X1b : X1a;
  const float* X2 = blockIdx.z ? X2b : X2a;
  float* C = blockIdx.z ? Cb : Ca;
  const int bn = blockIdx.x * 64;
  const int bm = blockIdx.y * 64;
  __shared__ float Ws[32][65];
  __shared__ float Xs[32][64];
  const int t = threadIdx.x;
  const int tm = (t >> 4) << 2;
  const int tn = (t & 15) << 2;
  float acc[4][4] = {{0.f}};
  for (int k0 = 0; k0 < 256; k0 += 32) {
#pragma unroll
    for (int i = 0; i < 8; ++i) {
      int e = t + i * 256;
      Ws[e & 31][e >> 5] = W[(size_t)(bm + (e >> 5)) * 256 + k0 + (e & 31)];
    }
    const float* Xp = (k0 < 128) ? X1 : X2;
    const int kb = k0 & 127;
#pragma unroll
    for (int i = 0; i < 2; ++i) {
      int e = t + i * 256;
      int r = e >> 4, c4 = e & 15;
      *(float4*)&Xs[r][c4 * 4] = *(const float4*)&Xp[(size_t)(kb + r) * NN + bn + c4 * 4];
    }
    __syncthreads();
#pragma unroll
    for (int kk = 0; kk < 32; ++kk) {
      float a[4];
      a[0] = Ws[kk][tm]; a[1] = Ws[kk][tm + 1]; a[2] = Ws[kk][tm + 2]; a[3] = Ws[kk][tm + 3];
      float4 b4 = *(const float4*)&Xs[kk][tn];
      float bb[4] = {b4.x, b4.y, b4.z, b4.w};
#pragma unroll
      for (int i = 0; i < 4; ++i)
#pragma unroll
        for (int j = 0; j < 4; ++j) acc[i][j] += a[i] * bb[j];
    }
    __syncthreads();
  }
#pragma unroll
  for (int i = 0; i < 4; ++i) {
    float bias = Bv[bm + tm + i];
    float4 r = make_float4(acc[i][0] + bias, acc[i][1] + bias, acc[i][2] + bias, acc[i][3] + bias);
    *(float4*)&C[(size_t)(bm + tm + i) * NN + bn + tn] = r;
  }
}

// ---------------------------------------------------------------------------
// InstanceNorm stats: mean + rsqrt(var+eps) per channel (256 ch x 2 descs)
// ---------------------------------------------------------------------------
__global__ __launch_bounds__(256) void stats_kernel(
    const float* __restrict__ h0, const float* __restrict__ h1,
    float* __restrict__ s0, float* __restrict__ s1) {
  const float* Hp = blockIdx.y ? h1 : h0;
  float* st = blockIdx.y ? s1 : s0;
  const int c = blockIdx.x;
  const float* row = Hp + (size_t)c * NN;
  float s = 0.f, ss = 0.f;
  for (int i = threadIdx.x; i < NN; i += 256) {
    float v = row[i];
    s += v; ss += v * v;
  }
#pragma unroll
  for (int off = 32; off; off >>= 1) {
    s += __shfl_down(s, off);
    ss += __shfl_down(ss, off);
  }
  __shared__ float as[4], as2[4];
  const int w = threadIdx.x >> 6;
  if ((threadIdx.x & 63) == 0) { as[w] = s; as2[w] = ss; }
  __syncthreads();
  if (threadIdx.x == 0) {
    float S = as[0] + as[1] + as[2] + as[3];
    float SS = as2[0] + as2[1] + as2[2] + as2[3];
    float mean = S * (1.0f / NN);
    float var = fmaxf(SS * (1.0f / NN) - mean * mean, 0.f);
    st[c * 2] = mean;
    st[c * 2 + 1] = rsqrtf(var + 1e-5f);
  }
}

// ---------------------------------------------------------------------------
// MLP layer 2 + residual: D += W2[128][256] @ relu((H-mean)*rstd) + b2
// ---------------------------------------------------------------------------
__global__ __launch_bounds__(256) void mlp2_kernel(
    const float* __restrict__ W, const float* __restrict__ Bv,
    const float* __restrict__ Ha, const float* __restrict__ sa, float* __restrict__ Da,
    const float* __restrict__ Hb, const float* __restrict__ sb, float* __restrict__ Db) {
  const float* Hp = blockIdx.z ? Hb : Ha;
  const float* st = blockIdx.z ? sb : sa;
  float* Dp = blockIdx.z ? Db : Da;
  const int bn = blockIdx.x * 64;
  const int bm = blockIdx.y * 64;
  __shared__ float Ws[32][65];
  __shared__ float Xs[32][64];
  const int t = threadIdx.x;
  const int tm = (t >> 4) << 2;
  const int tn = (t & 15) << 2;
  float acc[4][4] = {{0.f}};
  for (int k0 = 0; k0 < 256; k0 += 32) {
#pragma unroll
    for (int i = 0; i < 8; ++i) {
      int e = t + i * 256;
      Ws[e & 31][e >> 5] = W[(size_t)(bm + (e >> 5)) * 256 + k0 + (e & 31)];
    }
#pragma unroll
    for (int i = 0; i < 2; ++i) {
      int e = t + i * 256;
      int r = e >> 4, c4 = e & 15;
      const int kc = k0 + r;
      float mean = st[kc * 2];
      float rstd = st[kc * 2 + 1];
      float4 v = *(const float4*)&Hp[(size_t)kc * NN + bn + c4 * 4];
      v.x = fmaxf((v.x - mean) * rstd, 0.f);
      v.y = fmaxf((v.y - mean) * rstd, 0.f);
      v.z = fmaxf((v.z - mean) * rstd, 0.f);
      v.w = fmaxf((v.w - mean) * rstd, 0.f);
      *(float4*)&Xs[r][c4 * 4] = v;
    }
    __syncthreads();
#pragma unroll
    for (int kk = 0; kk < 32; ++kk) {
      float a[4];
      a[0] = Ws[kk][tm]; a[1] = Ws[kk][tm + 1]; a[2] = Ws[kk][tm + 2]; a[3] = Ws[kk][tm + 3];
      float4 b4 = *(const float4*)&Xs[kk][tn];
      float bb[4] = {b4.x, b4.y, b4.z, b4.w};
#pragma unroll
      for (int i = 0; i < 4; ++i)
#pragma unroll
        for (int j = 0; j < 4; ++j) acc[i][j] += a[i] * bb[j];
    }
    __syncthreads();
  }
#pragma unroll
  for (int i = 0; i < 4; ++i) {
    float bias = Bv[bm + tm + i];
    float4* dst = (float4*)&Dp[(size_t)(bm + tm + i) * NN + bn + tn];
    float4 old = *dst;
    old.x += acc[i][0] + bias;
    old.y += acc[i][1] + bias;
    old.z += acc[i][2] + bias;
    old.w += acc[i][3] + bias;
    *dst = old;
  }
}

// ---------------------------------------------------------------------------
extern "C" void kernel_launch(void* const* d_in, const int* in_sizes, int n_in,
                              void* d_out, int out_size, void* d_ws, size_t ws_size,
                              hipStream_t stream) {
  const float* desc0 = (const float*)d_in[0];
  const float* desc1 = (const float*)d_in[1];
  const float* Wq = (const float*)d_in[2];
  const float* bq = (const float*)d_in[3];
  const float* Wk = (const float*)d_in[4];
  const float* bk = (const float*)d_in[5];
  const float* Wv = (const float*)d_in[6];
  const float* bv = (const float*)d_in[7];
  const float* Wm = (const float*)d_in[8];
  const float* bmv = (const float*)d_in[9];
  const float* W1 = (const float*)d_in[10];
  const float* b1 = (const float*)d_in[11];
  const float* W2 = (const float*)d_in[12];
  const float* b2 = (const float*)d_in[13];

  float* out0 = (float*)d_out;
  float* out1 = out0 + (size_t)DDIM * NN;
  float* ws = (float*)d_ws;
  const size_t S = (size_t)DDIM * NN;  // 262144
  float* mg0 = ws + 0 * S;
  float* mg1 = ws + 1 * S;
  float* mm0 = ws + 2 * S;
  float* mm1 = ws + 3 * S;
  float* h0 = ws + 4 * S;   // 2*S
  float* h1 = ws + 6 * S;   // 2*S
  float* s0 = ws + 8 * S;
  float* s1 = s0 + 512;
  float* Pm = ws + 8 * S + 1024;   // 65536
  float* Pl = Pm + 65536;          // 65536
  float* Po = Pl + 65536;          // 2097152
  unsigned short* ub = (unsigned short*)(Po + 2097152);
  unsigned short* Qb0 = ub;                 // 262144 each
  unsigned short* Qb1 = ub + 1 * 262144;
  unsigned short* Kt0 = ub + 2 * 262144;
  unsigned short* Kt1 = ub + 3 * 262144;
  unsigned short* Vb0 = ub + 4 * 262144;
  unsigned short* Vb1 = ub + 5 * 262144;

  (void)hipMemcpyAsync(out0, desc0, S * sizeof(float), hipMemcpyDeviceToDevice, stream);
  (void)hipMemcpyAsync(out1, desc1, S * sizeof(float), hipMemcpyDeviceToDevice, stream);

  for (int l = 0; l < NL; ++l) {
    const int cross = l & 1;
    const float* wq = Wq + (size_t)l * DDIM * DDIM;
    const float* wk = Wk + (size_t)l * DDIM * DDIM;
    const float* wv = Wv + (size_t)l * DDIM * DDIM;
    const float* wm = Wm + (size_t)l * DDIM * DDIM;
    const float* bqp = bq + (size_t)l * DDIM;
    const float* bkp = bk + (size_t)l * DDIM;
    const float* bvp = bv + (size_t)l * DDIM;
    const float* bmp = bmv + (size_t)l * DDIM;

    QOps Pq;
    Pq.op[0] = {wq, bqp, out0, Qb0, 0};
    Pq.op[1] = {wq, bqp, out1, Qb1, 0};
    Pq.op[2] = {wk, bkp, out0, Kt0, 1};
    Pq.op[3] = {wk, bkp, out1, Kt1, 1};
    Pq.op[4] = {wv, bvp, out0, Vb0, 2};
    Pq.op[5] = {wv, bvp, out1, Vb1, 2};
    qkv_gemm_kernel<<<dim3(32, 2, 6), 256, 0, stream>>>(Pq);

    attn_mfma_kernel<<<dim3(16, 4, 8), 256, 0, stream>>>(
        Qb0, Kt0, Vb0, Qb1, Kt1, Vb1, Pm, Pl, Po, cross);
    attn_merge_kernel<<<dim3(8, 8), 256, 0, stream>>>(Pm, Pl, Po, mg0, mg1);

    GOps Pmm;
    Pmm.op[0] = {wm, bmp, mg0, mm0};
    Pmm.op[1] = {wm, bmp, mg1, mm1};
    Pmm.op[2] = Pmm.op[0]; Pmm.op[3] = Pmm.op[0]; Pmm.op[4] = Pmm.op[0]; Pmm.op[5] = Pmm.op[0];
    gemm128_kernel<<<dim3(32, 2, 2), 256, 0, stream>>>(Pmm);

    mlp1_kernel<<<dim3(32, 4, 2), 256, 0, stream>>>(
        W1 + (size_t)l * 256 * 256, b1 + (size_t)l * 256, out0, mm0, h0, out1, mm1, h1);

    stats_kernel<<<dim3(256, 2), 256, 0, stream>>>(h0, h1, s0, s1);

    mlp2_kernel<<<dim3(32, 2, 2), 256, 0, stream>>>(
        W2 + (size_t)l * 128 * 256, b2 + (size_t)l * 128, h0, s0, out0, h1, s1, out1);
  }
}

// Round 4
// 604.377 us; speedup vs baseline: 4.5730x; 1.3395x over previous
//
#include <hip/hip_runtime.h>

#define NN 2048
#define DDIM 128
#define NHEAD 4
#define DH 32
#define NL 6

typedef __attribute__((ext_vector_type(8))) __bf16 bf16x8;
typedef __attribute__((ext_vector_type(4))) float f32x4;

__device__ __forceinline__ unsigned int f2bf(float x) {
  unsigned int u = __float_as_uint(x);
  u += 0x7fff + ((u >> 16) & 1);   // RNE
  return u >> 16;
}
__device__ __forceinline__ unsigned int pk2(float a, float b) {
  return f2bf(a) | (f2bf(b) << 16);
}
__device__ __forceinline__ float bf2f(unsigned short u) {
  return __uint_as_float(((unsigned int)u) << 16);
}

// ---------------------------------------------------------------------------
// Weight cast: all 6 weight tensors fp32 -> bf16, row-major preserved.
// Segments (element offsets): WQ 0, WK 98304, WV 196608, WM 294912,
// W1 393216 (len 393216), W2 786432 (len 196608). Total 983040.
// ---------------------------------------------------------------------------
__global__ __launch_bounds__(256) void wcast_kernel(
    const float* __restrict__ Wq, const float* __restrict__ Wk,
    const float* __restrict__ Wv, const float* __restrict__ Wm,
    const float* __restrict__ W1, const float* __restrict__ W2,
    unsigned short* __restrict__ out) {
  int idx = (blockIdx.x * 256 + threadIdx.x) * 4;
  if (idx >= 983040) return;
  const float* src; int off;
  if (idx < 98304)       { src = Wq; off = idx; }
  else if (idx < 196608) { src = Wk; off = idx - 98304; }
  else if (idx < 294912) { src = Wv; off = idx - 196608; }
  else if (idx < 393216) { src = Wm; off = idx - 294912; }
  else if (idx < 786432) { src = W1; off = idx - 393216; }
  else                   { src = W2; off = idx - 786432; }
  float4 v = *(const float4*)&src[off];
  uint2 p = { pk2(v.x, v.y), pk2(v.z, v.w) };
  *(uint2*)&out[idx] = p;
}

// ---------------------------------------------------------------------------
// desc fp32 [c][n] -> desc_T bf16 [n][128] (LDS tile transpose).
// Grid (32 n-tiles of 64, 2 descs), block 256.
// ---------------------------------------------------------------------------
__global__ __launch_bounds__(256) void desc_cast_kernel(
    const float* __restrict__ d0, const float* __restrict__ d1,
    unsigned short* __restrict__ t0, unsigned short* __restrict__ t1) {
  const float* D = blockIdx.y ? d1 : d0;
  unsigned short* T = blockIdx.y ? t1 : t0;
  const int n0 = blockIdx.x * 64;
  const int t = threadIdx.x;
  __shared__ __align__(16) unsigned short L[64 * 136];
#pragma unroll
  for (int i = 0; i < 8; ++i) {
    int idx = t + i * 256;               // 2048 float4
    int c = idx >> 4, nj = (idx & 15) * 4;
    float4 v = *(const float4*)&D[(size_t)c * NN + n0 + nj];
    L[(nj + 0) * 136 + c] = (unsigned short)f2bf(v.x);
    L[(nj + 1) * 136 + c] = (unsigned short)f2bf(v.y);
    L[(nj + 2) * 136 + c] = (unsigned short)f2bf(v.z);
    L[(nj + 3) * 136 + c] = (unsigned short)f2bf(v.w);
  }
  __syncthreads();
#pragma unroll
  for (int i = 0; i < 4; ++i) {
    int idx = t + i * 256;               // 1024 x 8 shorts
    int n = idx >> 4, cj = (idx & 15) * 8;
    uint4 v = *(const uint4*)&L[n * 136 + cj];
    *(uint4*)&T[(size_t)(n0 + n) * 128 + cj] = v;
  }
}

// ---------------------------------------------------------------------------
// Unified bf16 MFMA GEMM. C[M][N] = W[M][K] @ X^T + bias, tile 64M x 128N,
// 4 waves, wave w owns n-range w*32 (2x 16-tiles), 4 m-tiles, K-step 32.
// B input is transposed bf16: X_T[n][ldb] (k contiguous).
// Modes: 0=Q (scaled, [h][32d][n]), 1=K ([h][n][32d]), 2=V ([h][32d][n]),
//        3=out_T bf16 [n][ldc], 4=mlp2 (normalize+relu staging from stats,
//        residual fp32 += into Cf, bf16 desc_T into Cb).
// ---------------------------------------------------------------------------
struct MOp {
  const unsigned short* A;   // bf16 W [M][K]
  const float* bias;         // [M]
  const unsigned short* B1;  // X_T [N][ldb]
  const unsigned short* B2;  // concat second half (k>=128) or null
  unsigned short* Cb;
  float* Cf;
  const float* Sp;           // stats partials (mode 4): [chunk*512 + c*2]
  int K, ldb, ldc, mode;
};
struct MOps8 { MOp op[8]; };

__global__ __launch_bounds__(256) void mfma_gemm_kernel(MOps8 P) {
  const MOp g = P.op[blockIdx.z];
  const int t = threadIdx.x;
  const int w = t >> 6, lane = t & 63;
  const int col = lane & 15, Qd = lane >> 4;
  const int bm = blockIdx.y * 64;
  const int bn = blockIdx.x * 128;

  __shared__ __align__(16) unsigned short Ws[64 * 40];
  __shared__ __align__(16) unsigned short Xs[128 * 40];
  __shared__ float meanL[256], rstdL[256];

  if (g.mode == 4) {
    float s = 0.f, ss = 0.f;
#pragma unroll
    for (int ch = 0; ch < 8; ++ch) {
      s += g.Sp[ch * 512 + t * 2];
      ss += g.Sp[ch * 512 + t * 2 + 1];
    }
    float mean = s * (1.0f / NN);
    float var = fmaxf(ss * (1.0f / NN) - mean * mean, 0.f);
    meanL[t] = mean;
    rstdL[t] = rsqrtf(var + 1e-5f);
  }

  f32x4 acc[4][2];
#pragma unroll
  for (int mt = 0; mt < 4; ++mt)
#pragma unroll
    for (int nt = 0; nt < 2; ++nt) acc[mt][nt] = (f32x4){0.f, 0.f, 0.f, 0.f};

  for (int k0 = 0; k0 < g.K; k0 += 32) {
    __syncthreads();
    {
      int row = t >> 2, ko = (t & 3) * 8;
      *(uint4*)&Ws[row * 40 + ko] =
          *(const uint4*)&g.A[(size_t)(bm + row) * g.K + k0 + ko];
    }
    const unsigned short* Bp = g.B1;
    int kk0 = k0;
    if (g.B2 && k0 >= 128) { Bp = g.B2; kk0 = k0 - 128; }
#pragma unroll
    for (int i = 0; i < 2; ++i) {
      int idx = t + i * 256;
      int row = idx >> 2, ko = (idx & 3) * 8;
      uint4 v = *(const uint4*)&Bp[(size_t)(bn + row) * g.ldb + kk0 + ko];
      if (g.mode == 4) {
        union { uint4 q; unsigned short us[8]; } u;
        u.q = v;
#pragma unroll
        for (int j = 0; j < 8; ++j) {
          int k = k0 + ko + j;
          float x = bf2f(u.us[j]);
          x = fmaxf((x - meanL[k]) * rstdL[k], 0.f);
          u.us[j] = (unsigned short)f2bf(x);
        }
        v = u.q;
      }
      *(uint4*)&Xs[row * 40 + ko] = v;
    }
    __syncthreads();
    bf16x8 af[4], bfr[2];
#pragma unroll
    for (int mt = 0; mt < 4; ++mt)
      af[mt] = *(const bf16x8*)&Ws[(mt * 16 + col) * 40 + Qd * 8];
#pragma unroll
    for (int nt = 0; nt < 2; ++nt)
      bfr[nt] = *(const bf16x8*)&Xs[(w * 32 + nt * 16 + col) * 40 + Qd * 8];
#pragma unroll
    for (int mt = 0; mt < 4; ++mt)
#pragma unroll
      for (int nt = 0; nt < 2; ++nt)
        acc[mt][nt] = __builtin_amdgcn_mfma_f32_16x16x32_bf16(af[mt], bfr[nt], acc[mt][nt], 0, 0, 0);
  }

#pragma unroll
  for (int mt = 0; mt < 4; ++mt) {
    const int c0 = bm + mt * 16 + Qd * 4;
    const float b0 = g.bias[c0], b1 = g.bias[c0 + 1];
    const float b2 = g.bias[c0 + 2], b3 = g.bias[c0 + 3];
#pragma unroll
    for (int nt = 0; nt < 2; ++nt) {
      const int n = bn + w * 32 + nt * 16 + col;
      f32x4 a = acc[mt][nt];
      float v0 = a[0] + b0, v1 = a[1] + b1, v2 = a[2] + b2, v3 = a[3] + b3;
      if (g.mode <= 2) {
        if (g.mode == 0) {
          const float sc = 0.17677669529663687f;
          v0 *= sc; v1 *= sc; v2 *= sc; v3 *= sc;
        }
        const int d = c0 >> 2;   // c0 is 4-aligned; h = r
        if (g.mode == 1) {
          g.Cb[((size_t)0 * NN + n) * 32 + d] = (unsigned short)f2bf(v0);
          g.Cb[((size_t)1 * NN + n) * 32 + d] = (unsigned short)f2bf(v1);
          g.Cb[((size_t)2 * NN + n) * 32 + d] = (unsigned short)f2bf(v2);
          g.Cb[((size_t)3 * NN + n) * 32 + d] = (unsigned short)f2bf(v3);
        } else {
          g.Cb[(size_t)(0 * 32 + d) * NN + n] = (unsigned short)f2bf(v0);
          g.Cb[(size_t)(1 * 32 + d) * NN + n] = (unsigned short)f2bf(v1);
          g.Cb[(size_t)(2 * 32 + d) * NN + n] = (unsigned short)f2bf(v2);
          g.Cb[(size_t)(3 * 32 + d) * NN + n] = (unsigned short)f2bf(v3);
        }
      } else if (g.mode == 3) {
        uint2 pv = { pk2(v0, v1), pk2(v2, v3) };
        *(uint2*)&g.Cb[(size_t)n * g.ldc + c0] = pv;
      } else {
        float* dp = g.Cf;
        float o0 = dp[(size_t)(c0 + 0) * NN + n] + v0;
        float o1 = dp[(size_t)(c0 + 1) * NN + n] + v1;
        float o2 = dp[(size_t)(c0 + 2) * NN + n] + v2;
        float o3 = dp[(size_t)(c0 + 3) * NN + n] + v3;
        dp[(size_t)(c0 + 0) * NN + n] = o0;
        dp[(size_t)(c0 + 1) * NN + n] = o1;
        dp[(size_t)(c0 + 2) * NN + n] = o2;
        dp[(size_t)(c0 + 3) * NN + n] = o3;
        uint2 pv = { pk2(o0, o1), pk2(o2, o3) };
        *(uint2*)&g.Cb[(size_t)n * 128 + c0] = pv;
      }
    }
  }
}

// ---------------------------------------------------------------------------
// MFMA flash attention (bf16) — as R3, but partial O stored transposed
// PoT[plane][q][32d] with float4 stores.
// ---------------------------------------------------------------------------
__global__ __launch_bounds__(256) void attn_mfma_kernel(
    const unsigned short* __restrict__ Qb0, const unsigned short* __restrict__ Kt0,
    const unsigned short* __restrict__ Vb0, const unsigned short* __restrict__ Qb1,
    const unsigned short* __restrict__ Kt1, const unsigned short* __restrict__ Vb1,
    float* __restrict__ Pm, float* __restrict__ Pl, float* __restrict__ PoT, int cross) {
  const int z = blockIdx.z, desc = z >> 2, h = z & 3;
  const int cy = blockIdx.y;
  const int t = threadIdx.x;
  const int wid = t >> 6, lane = t & 63;
  const int col = lane & 15, Qd = lane >> 4;
  const int q0w = blockIdx.x * 128 + wid * 32;

  const unsigned short* Qb = desc ? Qb1 : Qb0;
  const int s = cross ? (1 - desc) : desc;
  const unsigned short* Kt = s ? Kt1 : Kt0;
  const unsigned short* Vb = s ? Vb1 : Vb0;

  __shared__ __align__(16) unsigned short SM[7424];
  unsigned short* KtL = SM;
  unsigned short* VL = SM + 2560;
  unsigned short* PL = SM + 4864 + wid * 640;

  bf16x8 bq[2];
#pragma unroll
  for (int g = 0; g < 2; ++g) {
    union { unsigned short u[8]; bf16x8 v; } tmp;
#pragma unroll
    for (int j = 0; j < 8; ++j)
      tmp.u[j] = Qb[(size_t)(h * 32 + Qd * 8 + j) * NN + q0w + g * 16 + col];
    bq[g] = tmp.v;
  }

  f32x4 o[2][2];
#pragma unroll
  for (int g = 0; g < 2; ++g)
#pragma unroll
    for (int h2 = 0; h2 < 2; ++h2) o[g][h2] = (f32x4){0.f, 0.f, 0.f, 0.f};
  float m[2] = {-1e30f, -1e30f}, l[2] = {0.f, 0.f};

  const int kbase = cy * 512;
  for (int kc = 0; kc < 512; kc += 64) {
    __syncthreads();
    {
      const int key = t >> 2, d8 = (t & 3) * 8;
      *(uint4*)&KtL[key * 40 + d8] =
          *(const uint4*)&Kt[((size_t)h * NN + kbase + kc + key) * 32 + d8];
      const int dv = t >> 3, c8 = (t & 7) * 8;
      *(uint4*)&VL[dv * 72 + c8] =
          *(const uint4*)&Vb[(size_t)(h * 32 + dv) * NN + kbase + kc + c8];
    }
    __syncthreads();
#pragma unroll
    for (int sub = 0; sub < 2; ++sub) {
      bf16x8 aK0 = *(const bf16x8*)&KtL[(sub * 32 + col) * 40 + Qd * 8];
      bf16x8 aK1 = *(const bf16x8*)&KtL[(sub * 32 + 16 + col) * 40 + Qd * 8];
      bf16x8 av0 = *(const bf16x8*)&VL[col * 72 + sub * 32 + Qd * 8];
      bf16x8 av1 = *(const bf16x8*)&VL[(16 + col) * 72 + sub * 32 + Qd * 8];
#pragma unroll
      for (int g = 0; g < 2; ++g) {
        f32x4 zacc = {0.f, 0.f, 0.f, 0.f};
        f32x4 s0 = __builtin_amdgcn_mfma_f32_16x16x32_bf16(aK0, bq[g], zacc, 0, 0, 0);
        f32x4 s1 = __builtin_amdgcn_mfma_f32_16x16x32_bf16(aK1, bq[g], zacc, 0, 0, 0);
        float cm = fmaxf(fmaxf(fmaxf(s0[0], s0[1]), fmaxf(s0[2], s0[3])),
                         fmaxf(fmaxf(s1[0], s1[1]), fmaxf(s1[2], s1[3])));
        cm = fmaxf(cm, __shfl_xor(cm, 16));
        cm = fmaxf(cm, __shfl_xor(cm, 32));
        const float mn = fmaxf(m[g], cm);
        const float alpha = __expf(m[g] - mn);
        m[g] = mn;
        float p00 = __expf(s0[0] - mn), p01 = __expf(s0[1] - mn);
        float p02 = __expf(s0[2] - mn), p03 = __expf(s0[3] - mn);
        float p10 = __expf(s1[0] - mn), p11 = __expf(s1[1] - mn);
        float p12 = __expf(s1[2] - mn), p13 = __expf(s1[3] - mn);
        float us = (p00 + p01) + (p02 + p03) + (p10 + p11) + (p12 + p13);
        us += __shfl_xor(us, 16);
        us += __shfl_xor(us, 32);
        l[g] = l[g] * alpha + us;
        uint2 w0 = { pk2(p00, p01), pk2(p02, p03) };
        uint2 w1 = { pk2(p10, p11), pk2(p12, p13) };
        *(uint2*)&PL[col * 40 + Qd * 4] = w0;
        *(uint2*)&PL[col * 40 + 16 + Qd * 4] = w1;
        __threadfence_block();
        bf16x8 pb = *(const bf16x8*)&PL[col * 40 + Qd * 8];
        o[g][0] = o[g][0] * alpha;
        o[g][1] = o[g][1] * alpha;
        o[g][0] = __builtin_amdgcn_mfma_f32_16x16x32_bf16(av0, pb, o[g][0], 0, 0, 0);
        o[g][1] = __builtin_amdgcn_mfma_f32_16x16x32_bf16(av1, pb, o[g][1], 0, 0, 0);
        __threadfence_block();
      }
    }
  }

#pragma unroll
  for (int g = 0; g < 2; ++g) {
    const int q = q0w + g * 16 + col;
    if (Qd == 0) {
      const size_t pidx = (size_t)(z * 4 + cy) * NN + q;
      Pm[pidx] = m[g];
      Pl[pidx] = l[g];
    }
#pragma unroll
    for (int h2 = 0; h2 < 2; ++h2) {
      float4 st = make_float4(o[g][h2][0], o[g][h2][1], o[g][h2][2], o[g][h2][3]);
      *(float4*)&PoT[(((size_t)(z * 4 + cy)) * NN + q) * 32 + h2 * 16 + Qd * 4] = st;
    }
  }
}

// ---------------------------------------------------------------------------
// Merge 4 key-chunk partials -> mg_T bf16 [q][128] (channel = d*4 + h).
// Grid (8, 8=desc*4+h), block 256, thread = one q.
// ---------------------------------------------------------------------------
__global__ __launch_bounds__(256) void attn_merge_kernel(
    const float* __restrict__ Pm, const float* __restrict__ Pl,
    const float* __restrict__ PoT,
    unsigned short* __restrict__ mgT0, unsigned short* __restrict__ mgT1) {
  const int z = blockIdx.y;
  const int desc = z >> 2;
  const int h = z & 3;
  const int q = blockIdx.x * 256 + threadIdx.x;
  const size_t b = (size_t)z * 4 * NN + q;
  float m0v = Pm[b], m1v = Pm[b + NN], m2v = Pm[b + 2 * NN], m3v = Pm[b + 3 * NN];
  float M = fmaxf(fmaxf(m0v, m1v), fmaxf(m2v, m3v));
  float w0 = __expf(m0v - M), w1 = __expf(m1v - M);
  float w2 = __expf(m2v - M), w3 = __expf(m3v - M);
  float L = w0 * Pl[b] + w1 * Pl[b + NN] + w2 * Pl[b + 2 * NN] + w3 * Pl[b + 3 * NN];
  float inv = 1.0f / L;
  unsigned short* T = desc ? mgT1 : mgT0;
  const size_t p0 = ((size_t)(z * 4 + 0) * NN + q) * 32;
  const size_t p1 = ((size_t)(z * 4 + 1) * NN + q) * 32;
  const size_t p2 = ((size_t)(z * 4 + 2) * NN + q) * 32;
  const size_t p3 = ((size_t)(z * 4 + 3) * NN + q) * 32;
#pragma unroll
  for (int d4 = 0; d4 < 32; d4 += 4) {
    float4 x0 = *(const float4*)&PoT[p0 + d4];
    float4 x1 = *(const float4*)&PoT[p1 + d4];
    float4 x2 = *(const float4*)&PoT[p2 + d4];
    float4 x3 = *(const float4*)&PoT[p3 + d4];
    float r0 = (w0 * x0.x + w1 * x1.x + w2 * x2.x + w3 * x3.x) * inv;
    float r1 = (w0 * x0.y + w1 * x1.y + w2 * x2.y + w3 * x3.y) * inv;
    float r2 = (w0 * x0.z + w1 * x1.z + w2 * x2.z + w3 * x3.z) * inv;
    float r3 = (w0 * x0.w + w1 * x1.w + w2 * x2.w + w3 * x3.w) * inv;
    T[(size_t)q * 128 + (d4 + 0) * 4 + h] = (unsigned short)f2bf(r0);
    T[(size_t)q * 128 + (d4 + 1) * 4 + h] = (unsigned short)f2bf(r1);
    T[(size_t)q * 128 + (d4 + 2) * 4 + h] = (unsigned short)f2bf(r2);
    T[(size_t)q * 128 + (d4 + 3) * 4 + h] = (unsigned short)f2bf(r3);
  }
}

// ---------------------------------------------------------------------------
// InstanceNorm partial sums from H_T bf16 [n][256]: per (chunk of 256 n, c):
// Sp[chunk*512 + c*2] = sum, [+1] = sumsq.  Grid (8, 2 desc), block 256.
// ---------------------------------------------------------------------------
__global__ __launch_bounds__(256) void stats_part_kernel(
    const unsigned short* __restrict__ H0, const unsigned short* __restrict__ H1,
    float* __restrict__ Sp0, float* __restrict__ Sp1) {
  const unsigned short* H = blockIdx.y ? H1 : H0;
  float* Sp = blockIdx.y ? Sp1 : Sp0;
  const int nb = blockIdx.x * 256;
  const int c = threadIdx.x;
  float s = 0.f, ss = 0.f;
  for (int i = 0; i < 256; i += 4) {
    float x0 = bf2f(H[(size_t)(nb + i + 0) * 256 + c]);
    float x1 = bf2f(H[(size_t)(nb + i + 1) * 256 + c]);
    float x2 = bf2f(H[(size_t)(nb + i + 2) * 256 + c]);
    float x3 = bf2f(H[(size_t)(nb + i + 3) * 256 + c]);
    s += (x0 + x1) + (x2 + x3);
    ss += (x0 * x0 + x1 * x1) + (x2 * x2 + x3 * x3);
  }
  Sp[blockIdx.x * 512 + c * 2] = s;
  Sp[blockIdx.x * 512 + c * 2 + 1] = ss;
}

// ---------------------------------------------------------------------------
extern "C" void kernel_launch(void* const* d_in, const int* in_sizes, int n_in,
                              void* d_out, int out_size, void* d_ws, size_t ws_size,
                              hipStream_t stream) {
  const float* desc0 = (const float*)d_in[0];
  const float* desc1 = (const float*)d_in[1];
  const float* Wq = (const float*)d_in[2];
  const float* bq = (const float*)d_in[3];
  const float* Wk = (const float*)d_in[4];
  const float* bk = (const float*)d_in[5];
  const float* Wv = (const float*)d_in[6];
  const float* bv = (const float*)d_in[7];
  const float* Wm = (const float*)d_in[8];
  const float* bmv = (const float*)d_in[9];
  const float* W1 = (const float*)d_in[10];
  const float* b1 = (const float*)d_in[11];
  const float* W2 = (const float*)d_in[12];
  const float* b2 = (const float*)d_in[13];

  float* out0 = (float*)d_out;
  float* out1 = out0 + (size_t)DDIM * NN;
  const size_t S = (size_t)DDIM * NN;  // 262144

  float* fws = (float*)d_ws;
  float* Pm = fws;                     // 65536
  float* Pl = Pm + 65536;              // 65536
  float* PoT = Pl + 65536;             // 2097152
  float* Sp0 = PoT + 2097152;          // 4096
  float* Sp1 = Sp0 + 4096;             // 4096
  unsigned short* uws = (unsigned short*)(Sp1 + 4096);
  unsigned short* dT0 = uws;                     // each 262144
  unsigned short* dT1 = uws + 1 * 262144;
  unsigned short* Qb0 = uws + 2 * 262144;
  unsigned short* Qb1 = uws + 3 * 262144;
  unsigned short* Kt0 = uws + 4 * 262144;
  unsigned short* Kt1 = uws + 5 * 262144;
  unsigned short* Vb0 = uws + 6 * 262144;
  unsigned short* Vb1 = uws + 7 * 262144;
  unsigned short* mgT0 = uws + 8 * 262144;
  unsigned short* mgT1 = uws + 9 * 262144;
  unsigned short* mmT0 = uws + 10 * 262144;
  unsigned short* mmT1 = uws + 11 * 262144;
  unsigned short* HT0 = uws + 12 * 262144;       // 524288
  unsigned short* HT1 = HT0 + 524288;            // 524288
  unsigned short* Wbf = HT1 + 524288;            // 983040

  const int OWQ = 0, OWK = 98304, OWV = 196608, OWM = 294912, OW1 = 393216, OW2 = 786432;

  wcast_kernel<<<960, 256, 0, stream>>>(Wq, Wk, Wv, Wm, W1, W2, Wbf);
  desc_cast_kernel<<<dim3(32, 2), 256, 0, stream>>>(desc0, desc1, dT0, dT1);
  (void)hipMemcpyAsync(out0, desc0, S * sizeof(float), hipMemcpyDeviceToDevice, stream);
  (void)hipMemcpyAsync(out1, desc1, S * sizeof(float), hipMemcpyDeviceToDevice, stream);

  for (int l = 0; l < NL; ++l) {
    const int cross = l & 1;
    const unsigned short* wq = Wbf + OWQ + l * 16384;
    const unsigned short* wk = Wbf + OWK + l * 16384;
    const unsigned short* wv = Wbf + OWV + l * 16384;
    const unsigned short* wm = Wbf + OWM + l * 16384;
    const unsigned short* w1 = Wbf + OW1 + l * 65536;
    const unsigned short* w2 = Wbf + OW2 + l * 32768;
    const float* bqp = bq + (size_t)l * 128;
    const float* bkp = bk + (size_t)l * 128;
    const float* bvp = bv + (size_t)l * 128;
    const float* bmp = bmv + (size_t)l * 128;
    const float* b1p = b1 + (size_t)l * 256;
    const float* b2p = b2 + (size_t)l * 128;

    MOps8 Pq = {};
    Pq.op[0] = {wq, bqp, dT0, nullptr, Qb0, nullptr, nullptr, 128, 128, 0, 0};
    Pq.op[1] = {wq, bqp, dT1, nullptr, Qb1, nullptr, nullptr, 128, 128, 0, 0};
    Pq.op[2] = {wk, bkp, dT0, nullptr, Kt0, nullptr, nullptr, 128, 128, 0, 1};
    Pq.op[3] = {wk, bkp, dT1, nullptr, Kt1, nullptr, nullptr, 128, 128, 0, 1};
    Pq.op[4] = {wv, bvp, dT0, nullptr, Vb0, nullptr, nullptr, 128, 128, 0, 2};
    Pq.op[5] = {wv, bvp, dT1, nullptr, Vb1, nullptr, nullptr, 128, 128, 0, 2};
    mfma_gemm_kernel<<<dim3(16, 2, 6), 256, 0, stream>>>(Pq);

    attn_mfma_kernel<<<dim3(16, 4, 8), 256, 0, stream>>>(
        Qb0, Kt0, Vb0, Qb1, Kt1, Vb1, Pm, Pl, PoT, cross);
    attn_merge_kernel<<<dim3(8, 8), 256, 0, stream>>>(Pm, Pl, PoT, mgT0, mgT1);

    MOps8 Pw = {};
    Pw.op[0] = {wm, bmp, mgT0, nullptr, mmT0, nullptr, nullptr, 128, 128, 128, 3};
    Pw.op[1] = {wm, bmp, mgT1, nullptr, mmT1, nullptr, nullptr, 128, 128, 128, 3};
    mfma_gemm_kernel<<<dim3(16, 2, 2), 256, 0, stream>>>(Pw);

    MOps8 P1 = {};
    P1.op[0] = {w1, b1p, dT0, mmT0, HT0, nullptr, nullptr, 256, 128, 256, 3};
    P1.op[1] = {w1, b1p, dT1, mmT1, HT1, nullptr, nullptr, 256, 128, 256, 3};
    mfma_gemm_kernel<<<dim3(16, 4, 2), 256, 0, stream>>>(P1);

    stats_part_kernel<<<dim3(8, 2), 256, 0, stream>>>(HT0, HT1, Sp0, Sp1);

    MOps8 P2 = {};
    P2.op[0] = {w2, b2p, HT0, nullptr, dT0, out0, Sp0, 256, 256, 128, 4};
    P2.op[1] = {w2, b2p, HT1, nullptr, dT1, out1, Sp1, 256, 256, 128, 4};
    mfma_gemm_kernel<<<dim3(16, 2, 2), 256, 0, stream>>>(P2);
  }
}

// Round 5
// 503.423 us; speedup vs baseline: 5.4901x; 1.2005x over previous
//
#include <hip/hip_runtime.h>

#define NN 2048
#define DDIM 128
#define NHEAD 4
#define DH 32
#define NL 6

typedef __attribute__((ext_vector_type(8))) __bf16 bf16x8;
typedef __attribute__((ext_vector_type(4))) float f32x4;

__device__ __forceinline__ unsigned int f2bf(float x) {
  unsigned int u = __float_as_uint(x);
  u += 0x7fff + ((u >> 16) & 1);   // RNE
  return u >> 16;
}
__device__ __forceinline__ unsigned int pk2(float a, float b) {
  return f2bf(a) | (f2bf(b) << 16);
}
__device__ __forceinline__ float bf2f(unsigned short u) {
  return __uint_as_float(((unsigned int)u) << 16);
}

// ---------------------------------------------------------------------------
// Weight cast fp32->bf16.
// seg0 [0,294912): Wq|Wk|Wv (98304 each) -> Wqkv
// seg1 [294912,491520): W2 (196608) -> Wb2
// seg2 [491520,688128): W1[:, :, 0:128] -> Wmix cols 0..127 (row stride 256)
// ---------------------------------------------------------------------------
__global__ __launch_bounds__(256) void wcast_kernel(
    const float* __restrict__ Wq, const float* __restrict__ Wk,
    const float* __restrict__ Wv, const float* __restrict__ W1,
    const float* __restrict__ W2,
    unsigned short* __restrict__ Wqkv, unsigned short* __restrict__ Wb2,
    unsigned short* __restrict__ Wmix) {
  int idx = (blockIdx.x * 256 + threadIdx.x) * 4;
  if (idx >= 688128) return;
  const float* src; unsigned short* dst; int soff, doff;
  if (idx < 98304)       { src = Wq; soff = idx; dst = Wqkv; doff = idx; }
  else if (idx < 196608) { src = Wk; soff = idx - 98304; dst = Wqkv; doff = idx; }
  else if (idx < 294912) { src = Wv; soff = idx - 196608; dst = Wqkv; doff = idx; }
  else if (idx < 491520) { src = W2; soff = idx - 294912; dst = Wb2; doff = soff; }
  else {
    int f = idx - 491520;
    int l = f >> 15, rem = f & 32767;
    int i = rem >> 7, c = rem & 127;
    src = W1; soff = (l << 16) + (i << 8) + c;
    dst = Wmix; doff = (l << 16) + (i << 8) + c;
  }
  float4 v = *(const float4*)&src[soff];
  uint2 p = { pk2(v.x, v.y), pk2(v.z, v.w) };
  *(uint2*)&dst[doff] = p;
}

// ---------------------------------------------------------------------------
// Wfuse: Wmix[l][i][128+j] = bf16( sum_k W1[l][i][128+k] * Wm[l][k][j] )
// Grid (2 j-tiles, 4 i-tiles, 6 layers), block 256, fp32 accumulate.
// ---------------------------------------------------------------------------
__global__ __launch_bounds__(256) void wfuse_kernel(
    const float* __restrict__ W1, const float* __restrict__ Wm,
    unsigned short* __restrict__ Wmix) {
  const int l = blockIdx.z;
  const int bj = blockIdx.x * 64;
  const int bi = blockIdx.y * 64;
  __shared__ float Ws[32][65];
  __shared__ float Xs[32][64];
  const int t = threadIdx.x;
  const int ti = (t >> 4) << 2;
  const int tj = (t & 15) << 2;
  float acc[4][4] = {{0.f}};
  for (int k0 = 0; k0 < 128; k0 += 32) {
#pragma unroll
    for (int i = 0; i < 8; ++i) {
      int e = t + i * 256;
      int ii = e >> 5, kk = e & 31;
      Ws[kk][ii] = W1[(size_t)(l << 16) + (bi + ii) * 256 + 128 + k0 + kk];
    }
#pragma unroll
    for (int i = 0; i < 2; ++i) {
      int e = t + i * 256;
      int r = e >> 4, c4 = e & 15;
      *(float4*)&Xs[r][c4 * 4] = *(const float4*)&Wm[(size_t)l * 16384 + (k0 + r) * 128 + bj + c4 * 4];
    }
    __syncthreads();
#pragma unroll
    for (int kk = 0; kk < 32; ++kk) {
      float a[4];
      a[0] = Ws[kk][ti]; a[1] = Ws[kk][ti + 1]; a[2] = Ws[kk][ti + 2]; a[3] = Ws[kk][ti + 3];
      float4 b4 = *(const float4*)&Xs[kk][tj];
      float bb[4] = {b4.x, b4.y, b4.z, b4.w};
#pragma unroll
      for (int i = 0; i < 4; ++i)
#pragma unroll
        for (int j = 0; j < 4; ++j) acc[i][j] += a[i] * bb[j];
    }
    __syncthreads();
  }
#pragma unroll
  for (int i = 0; i < 4; ++i) {
    uint2 p = { pk2(acc[i][0], acc[i][1]), pk2(acc[i][2], acc[i][3]) };
    *(uint2*)&Wmix[(size_t)(l << 16) + (bi + ti + i) * 256 + 128 + bj + tj] = p;
  }
}

// b1m[l][i] = b1[l][i] + sum_k W1[l][i][128+k] * bm[l][k].  Grid 6 x 256.
__global__ __launch_bounds__(256) void b1fold_kernel(
    const float* __restrict__ W1, const float* __restrict__ bmv,
    const float* __restrict__ b1, float* __restrict__ b1m) {
  const int l = blockIdx.x;
  const int i = threadIdx.x;
  float acc = b1[l * 256 + i];
  const float* wr = &W1[(size_t)(l << 16) + i * 256 + 128];
  const float* bp = &bmv[l * 128];
  for (int k = 0; k < 128; k += 4) {
    acc += wr[k] * bp[k] + wr[k + 1] * bp[k + 1] + wr[k + 2] * bp[k + 2] + wr[k + 3] * bp[k + 3];
  }
  b1m[l * 256 + i] = acc;
}

// ---------------------------------------------------------------------------
// desc fp32 [c][n] -> desc_T bf16 [n][128], plus fp32 copy into residual out.
// Grid (32 n-tiles of 64, 2 descs), block 256.
// ---------------------------------------------------------------------------
__global__ __launch_bounds__(256) void desc_cast_kernel(
    const float* __restrict__ d0, const float* __restrict__ d1,
    unsigned short* __restrict__ t0, unsigned short* __restrict__ t1,
    float* __restrict__ o0, float* __restrict__ o1) {
  const float* D = blockIdx.y ? d1 : d0;
  unsigned short* T = blockIdx.y ? t1 : t0;
  float* O = blockIdx.y ? o1 : o0;
  const int n0 = blockIdx.x * 64;
  const int t = threadIdx.x;
  __shared__ __align__(16) unsigned short L[64 * 136];
#pragma unroll
  for (int i = 0; i < 8; ++i) {
    int idx = t + i * 256;
    int c = idx >> 4, nj = (idx & 15) * 4;
    float4 v = *(const float4*)&D[(size_t)c * NN + n0 + nj];
    *(float4*)&O[(size_t)c * NN + n0 + nj] = v;
    L[(nj + 0) * 136 + c] = (unsigned short)f2bf(v.x);
    L[(nj + 1) * 136 + c] = (unsigned short)f2bf(v.y);
    L[(nj + 2) * 136 + c] = (unsigned short)f2bf(v.z);
    L[(nj + 3) * 136 + c] = (unsigned short)f2bf(v.w);
  }
  __syncthreads();
#pragma unroll
  for (int i = 0; i < 4; ++i) {
    int idx = t + i * 256;
    int n = idx >> 4, cj = (idx & 15) * 8;
    uint4 v = *(const uint4*)&L[n * 136 + cj];
    *(uint4*)&T[(size_t)(n0 + n) * 128 + cj] = v;
  }
}

// ---------------------------------------------------------------------------
// Unified bf16 MFMA GEMM. Tile 64M x 128N, 4 waves.
// Modes: 0=Q (scaled, [h][32d][n]; also zeroes Sp-target via Cf when bx==by==0)
//        1=K ([h][n][32d])   2=V ([h][32d][n])
//        3=plain bf16 out_T [n][ldc]
//        4=mlp2: B-staging normalize+relu from accumulated stats Sp,
//          residual fp32 += into Cf, bf16 desc_T into Cb
//        5=mlp1: bf16 out_T [n][256] + per-channel sum/ssq atomics into Cf
// ---------------------------------------------------------------------------
struct MOp {
  const unsigned short* A;   // bf16 W [M][K]
  const float* bias;         // [M]
  const unsigned short* B1;  // X_T [N][ldb]
  const unsigned short* B2;  // concat second half (k>=128) or null
  unsigned short* Cb;
  float* Cf;
  const float* Sp;           // accumulated stats (mode 4): [c*2],[c*2+1]
  int K, ldb, ldc, mode;
};
struct MOps8 { MOp op[8]; };

__global__ __launch_bounds__(256) void mfma_gemm_kernel(MOps8 P) {
  const MOp g = P.op[blockIdx.z];
  const int t = threadIdx.x;
  const int w = t >> 6, lane = t & 63;
  const int col = lane & 15, Qd = lane >> 4;
  const int bm = blockIdx.y * 64;
  const int bn = blockIdx.x * 128;

  __shared__ __align__(16) unsigned short Ws[64 * 40];
  __shared__ __align__(16) unsigned short Xs[128 * 40];
  __shared__ float meanL[256], rstdL[256];
  __shared__ float swS[4][64], swQ[4][64];

  if (g.mode == 4) {
    float s = g.Sp[t * 2], ss = g.Sp[t * 2 + 1];
    float mean = s * (1.0f / NN);
    float var = fmaxf(ss * (1.0f / NN) - mean * mean, 0.f);
    meanL[t] = mean;
    rstdL[t] = rsqrtf(var + 1e-5f);
  }
  if (g.mode == 0 && g.Cf && blockIdx.x == 0 && blockIdx.y == 0) {
    g.Cf[t] = 0.f;
    g.Cf[t + 256] = 0.f;
  }

  f32x4 acc[4][2];
#pragma unroll
  for (int mt = 0; mt < 4; ++mt)
#pragma unroll
    for (int nt = 0; nt < 2; ++nt) acc[mt][nt] = (f32x4){0.f, 0.f, 0.f, 0.f};

  for (int k0 = 0; k0 < g.K; k0 += 32) {
    __syncthreads();
    {
      int row = t >> 2, ko = (t & 3) * 8;
      *(uint4*)&Ws[row * 40 + ko] =
          *(const uint4*)&g.A[(size_t)(bm + row) * g.K + k0 + ko];
    }
    const unsigned short* Bp = g.B1;
    int kk0 = k0;
    if (g.B2 && k0 >= 128) { Bp = g.B2; kk0 = k0 - 128; }
#pragma unroll
    for (int i = 0; i < 2; ++i) {
      int idx = t + i * 256;
      int row = idx >> 2, ko = (idx & 3) * 8;
      uint4 v = *(const uint4*)&Bp[(size_t)(bn + row) * g.ldb + kk0 + ko];
      if (g.mode == 4) {
        union { uint4 q; unsigned short us[8]; } u;
        u.q = v;
#pragma unroll
        for (int j = 0; j < 8; ++j) {
          int k = k0 + ko + j;
          float x = bf2f(u.us[j]);
          x = fmaxf((x - meanL[k]) * rstdL[k], 0.f);
          u.us[j] = (unsigned short)f2bf(x);
        }
        v = u.q;
      }
      *(uint4*)&Xs[row * 40 + ko] = v;
    }
    __syncthreads();
    bf16x8 af[4], bfr[2];
#pragma unroll
    for (int mt = 0; mt < 4; ++mt)
      af[mt] = *(const bf16x8*)&Ws[(mt * 16 + col) * 40 + Qd * 8];
#pragma unroll
    for (int nt = 0; nt < 2; ++nt)
      bfr[nt] = *(const bf16x8*)&Xs[(w * 32 + nt * 16 + col) * 40 + Qd * 8];
#pragma unroll
    for (int mt = 0; mt < 4; ++mt)
#pragma unroll
      for (int nt = 0; nt < 2; ++nt)
        acc[mt][nt] = __builtin_amdgcn_mfma_f32_16x16x32_bf16(af[mt], bfr[nt], acc[mt][nt], 0, 0, 0);
  }

#pragma unroll
  for (int mt = 0; mt < 4; ++mt) {
    const int c0 = bm + mt * 16 + Qd * 4;
    const float b0 = g.bias[c0], b1 = g.bias[c0 + 1];
    const float b2 = g.bias[c0 + 2], b3 = g.bias[c0 + 3];
    float sA[4] = {0.f, 0.f, 0.f, 0.f}, sQ[4] = {0.f, 0.f, 0.f, 0.f};
#pragma unroll
    for (int nt = 0; nt < 2; ++nt) {
      const int n = bn + w * 32 + nt * 16 + col;
      f32x4 a = acc[mt][nt];
      float v0 = a[0] + b0, v1 = a[1] + b1, v2 = a[2] + b2, v3 = a[3] + b3;
      if (g.mode <= 2) {
        if (g.mode == 0) {
          const float sc = 0.17677669529663687f;
          v0 *= sc; v1 *= sc; v2 *= sc; v3 *= sc;
        }
        const int d = c0 >> 2;
        if (g.mode == 1) {
          g.Cb[((size_t)0 * NN + n) * 32 + d] = (unsigned short)f2bf(v0);
          g.Cb[((size_t)1 * NN + n) * 32 + d] = (unsigned short)f2bf(v1);
          g.Cb[((size_t)2 * NN + n) * 32 + d] = (unsigned short)f2bf(v2);
          g.Cb[((size_t)3 * NN + n) * 32 + d] = (unsigned short)f2bf(v3);
        } else {
          g.Cb[(size_t)(0 * 32 + d) * NN + n] = (unsigned short)f2bf(v0);
          g.Cb[(size_t)(1 * 32 + d) * NN + n] = (unsigned short)f2bf(v1);
          g.Cb[(size_t)(2 * 32 + d) * NN + n] = (unsigned short)f2bf(v2);
          g.Cb[(size_t)(3 * 32 + d) * NN + n] = (unsigned short)f2bf(v3);
        }
      } else if (g.mode == 3 || g.mode == 5) {
        uint2 pv = { pk2(v0, v1), pk2(v2, v3) };
        *(uint2*)&g.Cb[(size_t)n * g.ldc + c0] = pv;
        if (g.mode == 5) {
          sA[0] += v0; sA[1] += v1; sA[2] += v2; sA[3] += v3;
          sQ[0] += v0 * v0; sQ[1] += v1 * v1; sQ[2] += v2 * v2; sQ[3] += v3 * v3;
        }
      } else {
        float* dp = g.Cf;
        float o0 = dp[(size_t)(c0 + 0) * NN + n] + v0;
        float o1 = dp[(size_t)(c0 + 1) * NN + n] + v1;
        float o2 = dp[(size_t)(c0 + 2) * NN + n] + v2;
        float o3 = dp[(size_t)(c0 + 3) * NN + n] + v3;
        dp[(size_t)(c0 + 0) * NN + n] = o0;
        dp[(size_t)(c0 + 1) * NN + n] = o1;
        dp[(size_t)(c0 + 2) * NN + n] = o2;
        dp[(size_t)(c0 + 3) * NN + n] = o3;
        uint2 pv = { pk2(o0, o1), pk2(o2, o3) };
        *(uint2*)&g.Cb[(size_t)n * 128 + c0] = pv;
      }
    }
    if (g.mode == 5) {
#pragma unroll
      for (int r = 0; r < 4; ++r) {
#pragma unroll
        for (int off = 1; off < 16; off <<= 1) {
          sA[r] += __shfl_xor(sA[r], off);
          sQ[r] += __shfl_xor(sQ[r], off);
        }
      }
      if (col == 0) {
#pragma unroll
        for (int r = 0; r < 4; ++r) {
          swS[w][mt * 16 + Qd * 4 + r] = sA[r];
          swQ[w][mt * 16 + Qd * 4 + r] = sQ[r];
        }
      }
    }
  }
  if (g.mode == 5) {
    __syncthreads();
    if (t < 64) {
      float a = swS[0][t] + swS[1][t] + swS[2][t] + swS[3][t];
      float b = swQ[0][t] + swQ[1][t] + swQ[2][t] + swQ[3][t];
      atomicAdd(&g.Cf[(bm + t) * 2], a);
      atomicAdd(&g.Cf[(bm + t) * 2 + 1], b);
    }
  }
}

// ---------------------------------------------------------------------------
// MFMA flash attention (bf16), 16 q/wave, key-split across blocks.
// Grid: (32 q-tiles of 64, 4 key-chunks of 512, 8 = desc*4+head). Block 256.
// ---------------------------------------------------------------------------
__global__ __launch_bounds__(256) void attn_mfma_kernel(
    const unsigned short* __restrict__ Qb0, const unsigned short* __restrict__ Kt0,
    const unsigned short* __restrict__ Vb0, const unsigned short* __restrict__ Qb1,
    const unsigned short* __restrict__ Kt1, const unsigned short* __restrict__ Vb1,
    float* __restrict__ Pm, float* __restrict__ Pl, float* __restrict__ PoT, int cross) {
  const int z = blockIdx.z, desc = z >> 2, h = z & 3;
  const int cy = blockIdx.y;
  const int t = threadIdx.x;
  const int wid = t >> 6, lane = t & 63;
  const int col = lane & 15, Qd = lane >> 4;
  const int q0 = blockIdx.x * 64 + wid * 16;

  const unsigned short* Qb = desc ? Qb1 : Qb0;
  const int s = cross ? (1 - desc) : desc;
  const unsigned short* Kt = s ? Kt1 : Kt0;
  const unsigned short* Vb = s ? Vb1 : Vb0;

  __shared__ __align__(16) unsigned short SM[7424];
  unsigned short* KtL = SM;                    // 64 keys x 40
  unsigned short* VL = SM + 2560;              // 32 d x 72
  unsigned short* PL = SM + 4864 + wid * 640;  // 16 q x 40 per wave

  bf16x8 bq;
  {
    union { unsigned short u[8]; bf16x8 v; } tmp;
#pragma unroll
    for (int j = 0; j < 8; ++j)
      tmp.u[j] = Qb[(size_t)(h * 32 + Qd * 8 + j) * NN + q0 + col];
    bq = tmp.v;
  }

  f32x4 o[2];
  o[0] = (f32x4){0.f, 0.f, 0.f, 0.f};
  o[1] = (f32x4){0.f, 0.f, 0.f, 0.f};
  float m = -1e30f, l = 0.f;

  const int kbase = cy * 512;
  for (int kc = 0; kc < 512; kc += 64) {
    __syncthreads();
    {
      const int key = t >> 2, d8 = (t & 3) * 8;
      *(uint4*)&KtL[key * 40 + d8] =
          *(const uint4*)&Kt[((size_t)h * NN + kbase + kc + key) * 32 + d8];
      const int dv = t >> 3, c8 = (t & 7) * 8;
      *(uint4*)&VL[dv * 72 + c8] =
          *(const uint4*)&Vb[(size_t)(h * 32 + dv) * NN + kbase + kc + c8];
    }
    __syncthreads();
#pragma unroll
    for (int sub = 0; sub < 2; ++sub) {
      bf16x8 aK0 = *(const bf16x8*)&KtL[(sub * 32 + col) * 40 + Qd * 8];
      bf16x8 aK1 = *(const bf16x8*)&KtL[(sub * 32 + 16 + col) * 40 + Qd * 8];
      bf16x8 av0 = *(const bf16x8*)&VL[col * 72 + sub * 32 + Qd * 8];
      bf16x8 av1 = *(const bf16x8*)&VL[(16 + col) * 72 + sub * 32 + Qd * 8];
      f32x4 zacc = {0.f, 0.f, 0.f, 0.f};
      f32x4 s0 = __builtin_amdgcn_mfma_f32_16x16x32_bf16(aK0, bq, zacc, 0, 0, 0);
      f32x4 s1 = __builtin_amdgcn_mfma_f32_16x16x32_bf16(aK1, bq, zacc, 0, 0, 0);
      float cm = fmaxf(fmaxf(fmaxf(s0[0], s0[1]), fmaxf(s0[2], s0[3])),
                       fmaxf(fmaxf(s1[0], s1[1]), fmaxf(s1[2], s1[3])));
      cm = fmaxf(cm, __shfl_xor(cm, 16));
      cm = fmaxf(cm, __shfl_xor(cm, 32));
      const float mn = fmaxf(m, cm);
      const float alpha = __expf(m - mn);
      m = mn;
      float p00 = __expf(s0[0] - mn), p01 = __expf(s0[1] - mn);
      float p02 = __expf(s0[2] - mn), p03 = __expf(s0[3] - mn);
      float p10 = __expf(s1[0] - mn), p11 = __expf(s1[1] - mn);
      float p12 = __expf(s1[2] - mn), p13 = __expf(s1[3] - mn);
      float us = (p00 + p01) + (p02 + p03) + (p10 + p11) + (p12 + p13);
      us += __shfl_xor(us, 16);
      us += __shfl_xor(us, 32);
      l = l * alpha + us;
      uint2 w0 = { pk2(p00, p01), pk2(p02, p03) };
      uint2 w1 = { pk2(p10, p11), pk2(p12, p13) };
      *(uint2*)&PL[col * 40 + Qd * 4] = w0;
      *(uint2*)&PL[col * 40 + 16 + Qd * 4] = w1;
      __threadfence_block();
      bf16x8 pb = *(const bf16x8*)&PL[col * 40 + Qd * 8];
      o[0] = o[0] * alpha;
      o[1] = o[1] * alpha;
      o[0] = __builtin_amdgcn_mfma_f32_16x16x32_bf16(av0, pb, o[0], 0, 0, 0);
      o[1] = __builtin_amdgcn_mfma_f32_16x16x32_bf16(av1, pb, o[1], 0, 0, 0);
      __threadfence_block();
    }
  }

  const int q = q0 + col;
  if (Qd == 0) {
    const size_t pidx = (size_t)(z * 4 + cy) * NN + q;
    Pm[pidx] = m;
    Pl[pidx] = l;
  }
#pragma unroll
  for (int h2 = 0; h2 < 2; ++h2) {
    float4 st = make_float4(o[h2][0], o[h2][1], o[h2][2], o[h2][3]);
    *(float4*)&PoT[(((size_t)(z * 4 + cy)) * NN + q) * 32 + h2 * 16 + Qd * 4] = st;
  }
}

// ---------------------------------------------------------------------------
// Merge 4 key-chunk partials -> mg_T bf16 [q][128] (channel = d*4 + h).
// ---------------------------------------------------------------------------
__global__ __launch_bounds__(256) void attn_merge_kernel(
    const float* __restrict__ Pm, const float* __restrict__ Pl,
    const float* __restrict__ PoT,
    unsigned short* __restrict__ mgT0, unsigned short* __restrict__ mgT1) {
  const int z = blockIdx.y;
  const int desc = z >> 2;
  const int h = z & 3;
  const int q = blockIdx.x * 256 + threadIdx.x;
  const size_t b = (size_t)z * 4 * NN + q;
  float m0v = Pm[b], m1v = Pm[b + NN], m2v = Pm[b + 2 * NN], m3v = Pm[b + 3 * NN];
  float M = fmaxf(fmaxf(m0v, m1v), fmaxf(m2v, m3v));
  float w0 = __expf(m0v - M), w1 = __expf(m1v - M);
  float w2 = __expf(m2v - M), w3 = __expf(m3v - M);
  float L = w0 * Pl[b] + w1 * Pl[b + NN] + w2 * Pl[b + 2 * NN] + w3 * Pl[b + 3 * NN];
  float inv = 1.0f / L;
  unsigned short* T = desc ? mgT1 : mgT0;
  const size_t p0 = ((size_t)(z * 4 + 0) * NN + q) * 32;
  const size_t p1 = ((size_t)(z * 4 + 1) * NN + q) * 32;
  const size_t p2 = ((size_t)(z * 4 + 2) * NN + q) * 32;
  const size_t p3 = ((size_t)(z * 4 + 3) * NN + q) * 32;
#pragma unroll
  for (int d4 = 0; d4 < 32; d4 += 4) {
    float4 x0 = *(const float4*)&PoT[p0 + d4];
    float4 x1 = *(const float4*)&PoT[p1 + d4];
    float4 x2 = *(const float4*)&PoT[p2 + d4];
    float4 x3 = *(const float4*)&PoT[p3 + d4];
    float r0 = (w0 * x0.x + w1 * x1.x + w2 * x2.x + w3 * x3.x) * inv;
    float r1 = (w0 * x0.y + w1 * x1.y + w2 * x2.y + w3 * x3.y) * inv;
    float r2 = (w0 * x0.z + w1 * x1.z + w2 * x2.z + w3 * x3.z) * inv;
    float r3 = (w0 * x0.w + w1 * x1.w + w2 * x2.w + w3 * x3.w) * inv;
    T[(size_t)q * 128 + (d4 + 0) * 4 + h] = (unsigned short)f2bf(r0);
    T[(size_t)q * 128 + (d4 + 1) * 4 + h] = (unsigned short)f2bf(r1);
    T[(size_t)q * 128 + (d4 + 2) * 4 + h] = (unsigned short)f2bf(r2);
    T[(size_t)q * 128 + (d4 + 3) * 4 + h] = (unsigned short)f2bf(r3);
  }
}

// ---------------------------------------------------------------------------
extern "C" void kernel_launch(void* const* d_in, const int* in_sizes, int n_in,
                              void* d_out, int out_size, void* d_ws, size_t ws_size,
                              hipStream_t stream) {
  const float* desc0 = (const float*)d_in[0];
  const float* desc1 = (const float*)d_in[1];
  const float* Wq = (const float*)d_in[2];
  const float* bq = (const float*)d_in[3];
  const float* Wk = (const float*)d_in[4];
  const float* bk = (const float*)d_in[5];
  const float* Wv = (const float*)d_in[6];
  const float* bv = (const float*)d_in[7];
  const float* Wm = (const float*)d_in[8];
  const float* bmv = (const float*)d_in[9];
  const float* W1 = (const float*)d_in[10];
  const float* b1 = (const float*)d_in[11];
  const float* W2 = (const float*)d_in[12];
  const float* b2 = (const float*)d_in[13];

  float* out0 = (float*)d_out;
  float* out1 = out0 + (size_t)DDIM * NN;

  float* fws = (float*)d_ws;
  float* Pm = fws;                     // 65536
  float* Pl = Pm + 65536;              // 65536
  float* PoT = Pl + 65536;             // 2097152
  float* Sg0 = PoT + 2097152;          // 512
  float* Sg1 = Sg0 + 512;              // 512
  float* b1m = Sg1 + 512;              // 1536
  unsigned short* uws = (unsigned short*)(b1m + 1536);
  unsigned short* dT0 = uws;                     // 262144 each
  unsigned short* dT1 = uws + 1 * 262144;
  unsigned short* Qb0 = uws + 2 * 262144;
  unsigned short* Qb1 = uws + 3 * 262144;
  unsigned short* Kt0 = uws + 4 * 262144;
  unsigned short* Kt1 = uws + 5 * 262144;
  unsigned short* Vb0 = uws + 6 * 262144;
  unsigned short* Vb1 = uws + 7 * 262144;
  unsigned short* mgT0 = uws + 8 * 262144;
  unsigned short* mgT1 = uws + 9 * 262144;
  unsigned short* HT0 = uws + 10 * 262144;       // 524288
  unsigned short* HT1 = HT0 + 524288;            // 524288
  unsigned short* Wqkv = HT1 + 524288;           // 294912
  unsigned short* Wb2 = Wqkv + 294912;           // 196608
  unsigned short* Wmix = Wb2 + 196608;           // 393216

  wcast_kernel<<<672, 256, 0, stream>>>(Wq, Wk, Wv, W1, W2, Wqkv, Wb2, Wmix);
  wfuse_kernel<<<dim3(2, 4, 6), 256, 0, stream>>>(W1, Wm, Wmix);
  b1fold_kernel<<<6, 256, 0, stream>>>(W1, bmv, b1, b1m);
  desc_cast_kernel<<<dim3(32, 2), 256, 0, stream>>>(desc0, desc1, dT0, dT1, out0, out1);

  for (int l = 0; l < NL; ++l) {
    const int cross = l & 1;
    const unsigned short* wq = Wqkv + l * 16384;
    const unsigned short* wk = Wqkv + 98304 + l * 16384;
    const unsigned short* wv = Wqkv + 196608 + l * 16384;
    const unsigned short* wmx = Wmix + l * 65536;
    const unsigned short* w2 = Wb2 + l * 32768;
    const float* bqp = bq + (size_t)l * 128;
    const float* bkp = bk + (size_t)l * 128;
    const float* bvp = bv + (size_t)l * 128;
    const float* b1p = b1m + (size_t)l * 256;
    const float* b2p = b2 + (size_t)l * 128;

    MOps8 Pq = {};
    Pq.op[0] = {wq, bqp, dT0, nullptr, Qb0, Sg0, nullptr, 128, 128, 0, 0};
    Pq.op[1] = {wq, bqp, dT1, nullptr, Qb1, Sg1, nullptr, 128, 128, 0, 0};
    Pq.op[2] = {wk, bkp, dT0, nullptr, Kt0, nullptr, nullptr, 128, 128, 0, 1};
    Pq.op[3] = {wk, bkp, dT1, nullptr, Kt1, nullptr, nullptr, 128, 128, 0, 1};
    Pq.op[4] = {wv, bvp, dT0, nullptr, Vb0, nullptr, nullptr, 128, 128, 0, 2};
    Pq.op[5] = {wv, bvp, dT1, nullptr, Vb1, nullptr, nullptr, 128, 128, 0, 2};
    mfma_gemm_kernel<<<dim3(16, 2, 6), 256, 0, stream>>>(Pq);

    attn_mfma_kernel<<<dim3(32, 4, 8), 256, 0, stream>>>(
        Qb0, Kt0, Vb0, Qb1, Kt1, Vb1, Pm, Pl, PoT, cross);
    attn_merge_kernel<<<dim3(8, 8), 256, 0, stream>>>(Pm, Pl, PoT, mgT0, mgT1);

    MOps8 P1 = {};
    P1.op[0] = {wmx, b1p, dT0, mgT0, HT0, Sg0, nullptr, 256, 128, 256, 5};
    P1.op[1] = {wmx, b1p, dT1, mgT1, HT1, Sg1, nullptr, 256, 128, 256, 5};
    mfma_gemm_kernel<<<dim3(16, 4, 2), 256, 0, stream>>>(P1);

    MOps8 P2 = {};
    P2.op[0] = {w2, b2p, HT0, nullptr, dT0, out0, Sg0, 256, 256, 128, 4};
    P2.op[1] = {w2, b2p, HT1, nullptr, dT1, out1, Sg1, 256, 256, 128, 4};
    mfma_gemm_kernel<<<dim3(16, 2, 2), 256, 0, stream>>>(P2);
  }
}

// Round 6
// 464.831 us; speedup vs baseline: 5.9459x; 1.0830x over previous
//
#include <hip/hip_runtime.h>

#define NN 2048
#define DDIM 128
#define NHEAD 4
#define DH 32
#define NL 6

typedef __attribute__((ext_vector_type(8))) __bf16 bf16x8;
typedef __attribute__((ext_vector_type(4))) float f32x4;

__device__ __forceinline__ unsigned int f2bf(float x) {
  unsigned int u = __float_as_uint(x);
  u += 0x7fff + ((u >> 16) & 1);   // RNE
  return u >> 16;
}
__device__ __forceinline__ unsigned int pk2(float a, float b) {
  return f2bf(a) | (f2bf(b) << 16);
}
__device__ __forceinline__ float bf2f(unsigned short u) {
  return __uint_as_float(((unsigned int)u) << 16);
}

// ---------------------------------------------------------------------------
// Weight cast fp32->bf16.
// seg0 [0,294912): Wq|Wk|Wv (98304 each) -> Wqkv
// seg1 [294912,491520): W2 (196608) -> Wb2
// seg2 [491520,688128): W1[:, :, 0:128] -> Wmix cols 0..127 (row stride 256)
// ---------------------------------------------------------------------------
__global__ __launch_bounds__(256) void wcast_kernel(
    const float* __restrict__ Wq, const float* __restrict__ Wk,
    const float* __restrict__ Wv, const float* __restrict__ W1,
    const float* __restrict__ W2,
    unsigned short* __restrict__ Wqkv, unsigned short* __restrict__ Wb2,
    unsigned short* __restrict__ Wmix) {
  int idx = (blockIdx.x * 256 + threadIdx.x) * 4;
  if (idx >= 688128) return;
  const float* src; unsigned short* dst; int soff, doff;
  if (idx < 98304)       { src = Wq; soff = idx; dst = Wqkv; doff = idx; }
  else if (idx < 196608) { src = Wk; soff = idx - 98304; dst = Wqkv; doff = idx; }
  else if (idx < 294912) { src = Wv; soff = idx - 196608; dst = Wqkv; doff = idx; }
  else if (idx < 491520) { src = W2; soff = idx - 294912; dst = Wb2; doff = soff; }
  else {
    int f = idx - 491520;
    int l = f >> 15, rem = f & 32767;
    int i = rem >> 7, c = rem & 127;
    src = W1; soff = (l << 16) + (i << 8) + c;
    dst = Wmix; doff = (l << 16) + (i << 8) + c;
  }
  float4 v = *(const float4*)&src[soff];
  uint2 p = { pk2(v.x, v.y), pk2(v.z, v.w) };
  *(uint2*)&dst[doff] = p;
}

// ---------------------------------------------------------------------------
// Wfuse: Wmix[l][i][128+j] = bf16( sum_k W1[l][i][128+k] * Wm[l][k][j] )
// Grid (2 j-tiles, 4 i-tiles, 6 layers), block 256, fp32 accumulate.
// Block (0,0,l) additionally folds b1m[l][i] = b1 + W1b @ bm.
// ---------------------------------------------------------------------------
__global__ __launch_bounds__(256) void wfuse_kernel(
    const float* __restrict__ W1, const float* __restrict__ Wm,
    unsigned short* __restrict__ Wmix,
    const float* __restrict__ bmv, const float* __restrict__ b1,
    float* __restrict__ b1m) {
  const int l = blockIdx.z;
  const int bj = blockIdx.x * 64;
  const int bi = blockIdx.y * 64;
  __shared__ float Ws[32][65];
  __shared__ float Xs[32][64];
  const int t = threadIdx.x;
  const int ti = (t >> 4) << 2;
  const int tj = (t & 15) << 2;
  float acc[4][4] = {{0.f}};
  for (int k0 = 0; k0 < 128; k0 += 32) {
#pragma unroll
    for (int i = 0; i < 8; ++i) {
      int e = t + i * 256;
      int ii = e >> 5, kk = e & 31;
      Ws[kk][ii] = W1[(size_t)(l << 16) + (bi + ii) * 256 + 128 + k0 + kk];
    }
#pragma unroll
    for (int i = 0; i < 2; ++i) {
      int e = t + i * 256;
      int r = e >> 4, c4 = e & 15;
      *(float4*)&Xs[r][c4 * 4] = *(const float4*)&Wm[(size_t)l * 16384 + (k0 + r) * 128 + bj + c4 * 4];
    }
    __syncthreads();
#pragma unroll
    for (int kk = 0; kk < 32; ++kk) {
      float a[4];
      a[0] = Ws[kk][ti]; a[1] = Ws[kk][ti + 1]; a[2] = Ws[kk][ti + 2]; a[3] = Ws[kk][ti + 3];
      float4 b4 = *(const float4*)&Xs[kk][tj];
      float bb[4] = {b4.x, b4.y, b4.z, b4.w};
#pragma unroll
      for (int i = 0; i < 4; ++i)
#pragma unroll
        for (int j = 0; j < 4; ++j) acc[i][j] += a[i] * bb[j];
    }
    __syncthreads();
  }
#pragma unroll
  for (int i = 0; i < 4; ++i) {
    uint2 p = { pk2(acc[i][0], acc[i][1]), pk2(acc[i][2], acc[i][3]) };
    *(uint2*)&Wmix[(size_t)(l << 16) + (bi + ti + i) * 256 + 128 + bj + tj] = p;
  }
  if (blockIdx.x == 0 && blockIdx.y == 0) {
    float a = b1[l * 256 + t];
    const float* wr = &W1[(size_t)(l << 16) + t * 256 + 128];
    const float* bp = &bmv[l * 128];
    for (int k = 0; k < 128; k += 4)
      a += wr[k] * bp[k] + wr[k + 1] * bp[k + 1] + wr[k + 2] * bp[k + 2] + wr[k + 3] * bp[k + 3];
    b1m[l * 256 + t] = a;
  }
}

// ---------------------------------------------------------------------------
// desc fp32 [c][n] -> desc_T bf16 [n][128], plus fp32 copy into residual out.
// ---------------------------------------------------------------------------
__global__ __launch_bounds__(256) void desc_cast_kernel(
    const float* __restrict__ d0, const float* __restrict__ d1,
    unsigned short* __restrict__ t0, unsigned short* __restrict__ t1,
    float* __restrict__ o0, float* __restrict__ o1) {
  const float* D = blockIdx.y ? d1 : d0;
  unsigned short* T = blockIdx.y ? t1 : t0;
  float* O = blockIdx.y ? o1 : o0;
  const int n0 = blockIdx.x * 64;
  const int t = threadIdx.x;
  __shared__ __align__(16) unsigned short L[64 * 136];
#pragma unroll
  for (int i = 0; i < 8; ++i) {
    int idx = t + i * 256;
    int c = idx >> 4, nj = (idx & 15) * 4;
    float4 v = *(const float4*)&D[(size_t)c * NN + n0 + nj];
    *(float4*)&O[(size_t)c * NN + n0 + nj] = v;
    L[(nj + 0) * 136 + c] = (unsigned short)f2bf(v.x);
    L[(nj + 1) * 136 + c] = (unsigned short)f2bf(v.y);
    L[(nj + 2) * 136 + c] = (unsigned short)f2bf(v.z);
    L[(nj + 3) * 136 + c] = (unsigned short)f2bf(v.w);
  }
  __syncthreads();
#pragma unroll
  for (int i = 0; i < 4; ++i) {
    int idx = t + i * 256;
    int n = idx >> 4, cj = (idx & 15) * 8;
    uint4 v = *(const uint4*)&L[n * 136 + cj];
    *(uint4*)&T[(size_t)(n0 + n) * 128 + cj] = v;
  }
}

// ---------------------------------------------------------------------------
// Unified bf16 MFMA GEMM. Tile 64M x 128N, 4 waves.
// Modes: 0=Q (scaled, [h][32d][n]; zeroes stats buffer via Cf at block (0,0))
//        1=K ([h][n][32d])   2=V ([h][32d][n])
//        4=mlp2: B-staging normalize+relu from accumulated stats Sp,
//          residual fp32 += into Cf, bf16 desc_T into Cb
//        5=mlp1: bf16 out_T [n][256] + per-channel sum/ssq atomics into Cf
// ---------------------------------------------------------------------------
struct MOp {
  const unsigned short* A;   // bf16 W [M][K]
  const float* bias;         // [M]
  const unsigned short* B1;  // X_T [N][ldb]
  const unsigned short* B2;  // concat second half (k>=128) or null
  unsigned short* Cb;
  float* Cf;
  const float* Sp;           // accumulated stats (mode 4): [c*2],[c*2+1]
  int K, ldb, ldc, mode;
};
struct MOps8 { MOp op[8]; };

__global__ __launch_bounds__(256) void mfma_gemm_kernel(MOps8 P) {
  const MOp g = P.op[blockIdx.z];
  const int t = threadIdx.x;
  const int w = t >> 6, lane = t & 63;
  const int col = lane & 15, Qd = lane >> 4;
  const int bm = blockIdx.y * 64;
  const int bn = blockIdx.x * 128;

  __shared__ __align__(16) unsigned short Ws[64 * 40];
  __shared__ __align__(16) unsigned short Xs[128 * 40];
  __shared__ float meanL[256], rstdL[256];
  __shared__ float swS[4][64], swQ[4][64];

  if (g.mode == 4) {
    float s = g.Sp[t * 2], ss = g.Sp[t * 2 + 1];
    float mean = s * (1.0f / NN);
    float var = fmaxf(ss * (1.0f / NN) - mean * mean, 0.f);
    meanL[t] = mean;
    rstdL[t] = rsqrtf(var + 1e-5f);
  }
  if (g.mode == 0 && g.Cf && blockIdx.x == 0 && blockIdx.y == 0) {
    g.Cf[t] = 0.f;
    g.Cf[t + 256] = 0.f;
  }

  f32x4 acc[4][2];
#pragma unroll
  for (int mt = 0; mt < 4; ++mt)
#pragma unroll
    for (int nt = 0; nt < 2; ++nt) acc[mt][nt] = (f32x4){0.f, 0.f, 0.f, 0.f};

  for (int k0 = 0; k0 < g.K; k0 += 32) {
    __syncthreads();
    {
      int row = t >> 2, ko = (t & 3) * 8;
      *(uint4*)&Ws[row * 40 + ko] =
          *(const uint4*)&g.A[(size_t)(bm + row) * g.K + k0 + ko];
    }
    const unsigned short* Bp = g.B1;
    int kk0 = k0;
    if (g.B2 && k0 >= 128) { Bp = g.B2; kk0 = k0 - 128; }
#pragma unroll
    for (int i = 0; i < 2; ++i) {
      int idx = t + i * 256;
      int row = idx >> 2, ko = (idx & 3) * 8;
      uint4 v = *(const uint4*)&Bp[(size_t)(bn + row) * g.ldb + kk0 + ko];
      if (g.mode == 4) {
        union { uint4 q; unsigned short us[8]; } u;
        u.q = v;
#pragma unroll
        for (int j = 0; j < 8; ++j) {
          int k = k0 + ko + j;
          float x = bf2f(u.us[j]);
          x = fmaxf((x - meanL[k]) * rstdL[k], 0.f);
          u.us[j] = (unsigned short)f2bf(x);
        }
        v = u.q;
      }
      *(uint4*)&Xs[row * 40 + ko] = v;
    }
    __syncthreads();
    bf16x8 af[4], bfr[2];
#pragma unroll
    for (int mt = 0; mt < 4; ++mt)
      af[mt] = *(const bf16x8*)&Ws[(mt * 16 + col) * 40 + Qd * 8];
#pragma unroll
    for (int nt = 0; nt < 2; ++nt)
      bfr[nt] = *(const bf16x8*)&Xs[(w * 32 + nt * 16 + col) * 40 + Qd * 8];
#pragma unroll
    for (int mt = 0; mt < 4; ++mt)
#pragma unroll
      for (int nt = 0; nt < 2; ++nt)
        acc[mt][nt] = __builtin_amdgcn_mfma_f32_16x16x32_bf16(af[mt], bfr[nt], acc[mt][nt], 0, 0, 0);
  }

#pragma unroll
  for (int mt = 0; mt < 4; ++mt) {
    const int c0 = bm + mt * 16 + Qd * 4;
    const float b0 = g.bias[c0], b1 = g.bias[c0 + 1];
    const float b2 = g.bias[c0 + 2], b3 = g.bias[c0 + 3];
    float sA[4] = {0.f, 0.f, 0.f, 0.f}, sQ[4] = {0.f, 0.f, 0.f, 0.f};
#pragma unroll
    for (int nt = 0; nt < 2; ++nt) {
      const int n = bn + w * 32 + nt * 16 + col;
      f32x4 a = acc[mt][nt];
      float v0 = a[0] + b0, v1 = a[1] + b1, v2 = a[2] + b2, v3 = a[3] + b3;
      if (g.mode <= 2) {
        if (g.mode == 0) {
          const float sc = 0.17677669529663687f;
          v0 *= sc; v1 *= sc; v2 *= sc; v3 *= sc;
        }
        const int d = c0 >> 2;
        if (g.mode == 1) {
          g.Cb[((size_t)0 * NN + n) * 32 + d] = (unsigned short)f2bf(v0);
          g.Cb[((size_t)1 * NN + n) * 32 + d] = (unsigned short)f2bf(v1);
          g.Cb[((size_t)2 * NN + n) * 32 + d] = (unsigned short)f2bf(v2);
          g.Cb[((size_t)3 * NN + n) * 32 + d] = (unsigned short)f2bf(v3);
        } else {
          g.Cb[(size_t)(0 * 32 + d) * NN + n] = (unsigned short)f2bf(v0);
          g.Cb[(size_t)(1 * 32 + d) * NN + n] = (unsigned short)f2bf(v1);
          g.Cb[(size_t)(2 * 32 + d) * NN + n] = (unsigned short)f2bf(v2);
          g.Cb[(size_t)(3 * 32 + d) * NN + n] = (unsigned short)f2bf(v3);
        }
      } else if (g.mode == 5) {
        uint2 pv = { pk2(v0, v1), pk2(v2, v3) };
        *(uint2*)&g.Cb[(size_t)n * g.ldc + c0] = pv;
        sA[0] += v0; sA[1] += v1; sA[2] += v2; sA[3] += v3;
        sQ[0] += v0 * v0; sQ[1] += v1 * v1; sQ[2] += v2 * v2; sQ[3] += v3 * v3;
      } else {
        float* dp = g.Cf;
        float o0 = dp[(size_t)(c0 + 0) * NN + n] + v0;
        float o1 = dp[(size_t)(c0 + 1) * NN + n] + v1;
        float o2 = dp[(size_t)(c0 + 2) * NN + n] + v2;
        float o3 = dp[(size_t)(c0 + 3) * NN + n] + v3;
        dp[(size_t)(c0 + 0) * NN + n] = o0;
        dp[(size_t)(c0 + 1) * NN + n] = o1;
        dp[(size_t)(c0 + 2) * NN + n] = o2;
        dp[(size_t)(c0 + 3) * NN + n] = o3;
        uint2 pv = { pk2(o0, o1), pk2(o2, o3) };
        *(uint2*)&g.Cb[(size_t)n * 128 + c0] = pv;
      }
    }
    if (g.mode == 5) {
#pragma unroll
      for (int r = 0; r < 4; ++r) {
#pragma unroll
        for (int off = 1; off < 16; off <<= 1) {
          sA[r] += __shfl_xor(sA[r], off);
          sQ[r] += __shfl_xor(sQ[r], off);
        }
      }
      if (col == 0) {
#pragma unroll
        for (int r = 0; r < 4; ++r) {
          swS[w][mt * 16 + Qd * 4 + r] = sA[r];
          swQ[w][mt * 16 + Qd * 4 + r] = sQ[r];
        }
      }
    }
  }
  if (g.mode == 5) {
    __syncthreads();
    if (t < 64) {
      float a = swS[0][t] + swS[1][t] + swS[2][t] + swS[3][t];
      float b = swQ[0][t] + swQ[1][t] + swQ[2][t] + swQ[3][t];
      atomicAdd(&g.Cf[(bm + t) * 2], a);
      atomicAdd(&g.Cf[(bm + t) * 2 + 1], b);
    }
  }
}

// ---------------------------------------------------------------------------
// MFMA flash attention (bf16), key-split WITHIN the block, no global partials.
// Grid: (64 q-tiles of 32, 8 = desc*4+head). Block 256 = 4 waves:
//   wave wid: qsub = wid&1 (16 q), half = wid>>1 (keys half*1024..+1024).
// Each wave online-softmaxes its 1024 keys; halves merge via LDS at the end
// and write mg_T bf16 [q][128] (channel = d*4 + h) directly.
// ---------------------------------------------------------------------------
__global__ __launch_bounds__(256) void attn_mfma_kernel(
    const unsigned short* __restrict__ Qb0, const unsigned short* __restrict__ Kt0,
    const unsigned short* __restrict__ Vb0, const unsigned short* __restrict__ Qb1,
    const unsigned short* __restrict__ Kt1, const unsigned short* __restrict__ Vb1,
    unsigned short* __restrict__ mgT0, unsigned short* __restrict__ mgT1, int cross) {
  const int z = blockIdx.y, desc = z >> 2, h = z & 3;
  const int t = threadIdx.x;
  const int wid = t >> 6, lane = t & 63;
  const int col = lane & 15, Qd = lane >> 4;
  const int qsub = wid & 1, half = wid >> 1;
  const int qb = blockIdx.x * 32;
  const int q0 = qb + qsub * 16;

  const unsigned short* Qb = desc ? Qb1 : Qb0;
  const int s = cross ? (1 - desc) : desc;
  const unsigned short* Kt = s ? Kt1 : Kt0;
  const unsigned short* Vb = s ? Vb1 : Vb0;

  // SM shorts: KtA[64x40]@0, VA[32x72]@2560, KtB@4864, VB@7424,
  // P scratch 4x640 @9728. After main loop, floats alias the K/V region:
  // So[4][16][32]@0 (2048 f), m@2048(64 f), l@2112(64 f).
  __shared__ __align__(16) unsigned short SM[12288];
  unsigned short* KtL = SM + half * 4864;
  unsigned short* VL = SM + half * 4864 + 2560;
  unsigned short* PL = SM + 9728 + wid * 640;

  bf16x8 bq;
  {
    union { unsigned short u[8]; bf16x8 v; } tmp;
#pragma unroll
    for (int j = 0; j < 8; ++j)
      tmp.u[j] = Qb[(size_t)(h * 32 + Qd * 8 + j) * NN + q0 + col];
    bq = tmp.v;
  }

  f32x4 o[2];
  o[0] = (f32x4){0.f, 0.f, 0.f, 0.f};
  o[1] = (f32x4){0.f, 0.f, 0.f, 0.f};
  float m = -1e30f, l = 0.f;

  for (int it = 0; it < 16; ++it) {
    __syncthreads();
    {
      const int key = t >> 2, d8 = (t & 3) * 8;
      *(uint4*)&SM[key * 40 + d8] =
          *(const uint4*)&Kt[((size_t)h * NN + it * 64 + key) * 32 + d8];
      *(uint4*)&SM[4864 + key * 40 + d8] =
          *(const uint4*)&Kt[((size_t)h * NN + 1024 + it * 64 + key) * 32 + d8];
      const int dv = t >> 3, c8 = (t & 7) * 8;
      *(uint4*)&SM[2560 + dv * 72 + c8] =
          *(const uint4*)&Vb[(size_t)(h * 32 + dv) * NN + it * 64 + c8];
      *(uint4*)&SM[7424 + dv * 72 + c8] =
          *(const uint4*)&Vb[(size_t)(h * 32 + dv) * NN + 1024 + it * 64 + c8];
    }
    __syncthreads();
#pragma unroll
    for (int sub = 0; sub < 2; ++sub) {
      bf16x8 aK0 = *(const bf16x8*)&KtL[(sub * 32 + col) * 40 + Qd * 8];
      bf16x8 aK1 = *(const bf16x8*)&KtL[(sub * 32 + 16 + col) * 40 + Qd * 8];
      bf16x8 av0 = *(const bf16x8*)&VL[col * 72 + sub * 32 + Qd * 8];
      bf16x8 av1 = *(const bf16x8*)&VL[(16 + col) * 72 + sub * 32 + Qd * 8];
      f32x4 zacc = {0.f, 0.f, 0.f, 0.f};
      f32x4 s0 = __builtin_amdgcn_mfma_f32_16x16x32_bf16(aK0, bq, zacc, 0, 0, 0);
      f32x4 s1 = __builtin_amdgcn_mfma_f32_16x16x32_bf16(aK1, bq, zacc, 0, 0, 0);
      float cm = fmaxf(fmaxf(fmaxf(s0[0], s0[1]), fmaxf(s0[2], s0[3])),
                       fmaxf(fmaxf(s1[0], s1[1]), fmaxf(s1[2], s1[3])));
      cm = fmaxf(cm, __shfl_xor(cm, 16));
      cm = fmaxf(cm, __shfl_xor(cm, 32));
      const float mn = fmaxf(m, cm);
      const float alpha = __expf(m - mn);
      m = mn;
      float p00 = __expf(s0[0] - mn), p01 = __expf(s0[1] - mn);
      float p02 = __expf(s0[2] - mn), p03 = __expf(s0[3] - mn);
      float p10 = __expf(s1[0] - mn), p11 = __expf(s1[1] - mn);
      float p12 = __expf(s1[2] - mn), p13 = __expf(s1[3] - mn);
      float us = (p00 + p01) + (p02 + p03) + (p10 + p11) + (p12 + p13);
      us += __shfl_xor(us, 16);
      us += __shfl_xor(us, 32);
      l = l * alpha + us;
      uint2 w0 = { pk2(p00, p01), pk2(p02, p03) };
      uint2 w1 = { pk2(p10, p11), pk2(p12, p13) };
      *(uint2*)&PL[col * 40 + Qd * 4] = w0;
      *(uint2*)&PL[col * 40 + 16 + Qd * 4] = w1;
      __threadfence_block();
      bf16x8 pb = *(const bf16x8*)&PL[col * 40 + Qd * 8];
      o[0] = o[0] * alpha;
      o[1] = o[1] * alpha;
      o[0] = __builtin_amdgcn_mfma_f32_16x16x32_bf16(av0, pb, o[0], 0, 0, 0);
      o[1] = __builtin_amdgcn_mfma_f32_16x16x32_bf16(av1, pb, o[1], 0, 0, 0);
      __threadfence_block();
    }
  }

  // ---- in-block merge of the two key-halves ----
  __syncthreads();
  float* fS = (float*)SM;
#pragma unroll
  for (int h2 = 0; h2 < 2; ++h2) {
    *(float4*)&fS[wid * 512 + col * 32 + h2 * 16 + Qd * 4] =
        make_float4(o[h2][0], o[h2][1], o[h2][2], o[h2][3]);
  }
  if (Qd == 0) {
    fS[2048 + wid * 16 + col] = m;
    fS[2112 + wid * 16 + col] = l;
  }
  __syncthreads();
  {
    const int ql = t & 31, dg = t >> 5;       // 32 q x 8 d-groups
    const int q16 = ql & 15, qs = ql >> 4;
    const int wA = qs, wB = 2 + qs;
    float m0 = fS[2048 + wA * 16 + q16], m1 = fS[2048 + wB * 16 + q16];
    float l0 = fS[2112 + wA * 16 + q16], l1 = fS[2112 + wB * 16 + q16];
    float M = fmaxf(m0, m1);
    float w0 = __expf(m0 - M), w1 = __expf(m1 - M);
    float inv = 1.0f / (w0 * l0 + w1 * l1);
    unsigned short* T = desc ? mgT1 : mgT0;
    const int q = qb + ql;
#pragma unroll
    for (int r = 0; r < 4; ++r) {
      int d = dg * 4 + r;
      float v = (w0 * fS[wA * 512 + q16 * 32 + d] + w1 * fS[wB * 512 + q16 * 32 + d]) * inv;
      T[(size_t)q * 128 + d * 4 + h] = (unsigned short)f2bf(v);
    }
  }
}

// ---------------------------------------------------------------------------
extern "C" void kernel_launch(void* const* d_in, const int* in_sizes, int n_in,
                              void* d_out, int out_size, void* d_ws, size_t ws_size,
                              hipStream_t stream) {
  const float* desc0 = (const float*)d_in[0];
  const float* desc1 = (const float*)d_in[1];
  const float* Wq = (const float*)d_in[2];
  const float* bq = (const float*)d_in[3];
  const float* Wk = (const float*)d_in[4];
  const float* bk = (const float*)d_in[5];
  const float* Wv = (const float*)d_in[6];
  const float* bv = (const float*)d_in[7];
  const float* Wm = (const float*)d_in[8];
  const float* bmv = (const float*)d_in[9];
  const float* W1 = (const float*)d_in[10];
  const float* b1 = (const float*)d_in[11];
  const float* W2 = (const float*)d_in[12];
  const float* b2 = (const float*)d_in[13];

  float* out0 = (float*)d_out;
  float* out1 = out0 + (size_t)DDIM * NN;

  float* fws = (float*)d_ws;
  float* Sg0 = fws;                    // 512
  float* Sg1 = Sg0 + 512;              // 512
  float* b1m = Sg1 + 512;              // 1536
  unsigned short* uws = (unsigned short*)(b1m + 1536);
  unsigned short* dT0 = uws;                     // 262144 each
  unsigned short* dT1 = uws + 1 * 262144;
  unsigned short* Qb0 = uws + 2 * 262144;
  unsigned short* Qb1 = uws + 3 * 262144;
  unsigned short* Kt0 = uws + 4 * 262144;
  unsigned short* Kt1 = uws + 5 * 262144;
  unsigned short* Vb0 = uws + 6 * 262144;
  unsigned short* Vb1 = uws + 7 * 262144;
  unsigned short* mgT0 = uws + 8 * 262144;
  unsigned short* mgT1 = uws + 9 * 262144;
  unsigned short* HT0 = uws + 10 * 262144;       // 524288
  unsigned short* HT1 = HT0 + 524288;            // 524288
  unsigned short* Wqkv = HT1 + 524288;           // 294912
  unsigned short* Wb2 = Wqkv + 294912;           // 196608
  unsigned short* Wmix = Wb2 + 196608;           // 393216

  wcast_kernel<<<672, 256, 0, stream>>>(Wq, Wk, Wv, W1, W2, Wqkv, Wb2, Wmix);
  wfuse_kernel<<<dim3(2, 4, 6), 256, 0, stream>>>(W1, Wm, Wmix, bmv, b1, b1m);
  desc_cast_kernel<<<dim3(32, 2), 256, 0, stream>>>(desc0, desc1, dT0, dT1, out0, out1);

  for (int l = 0; l < NL; ++l) {
    const int cross = l & 1;
    const unsigned short* wq = Wqkv + l * 16384;
    const unsigned short* wk = Wqkv + 98304 + l * 16384;
    const unsigned short* wv = Wqkv + 196608 + l * 16384;
    const unsigned short* wmx = Wmix + l * 65536;
    const unsigned short* w2 = Wb2 + l * 32768;
    const float* bqp = bq + (size_t)l * 128;
    const float* bkp = bk + (size_t)l * 128;
    const float* bvp = bv + (size_t)l * 128;
    const float* b1p = b1m + (size_t)l * 256;
    const float* b2p = b2 + (size_t)l * 128;

    MOps8 Pq = {};
    Pq.op[0] = {wq, bqp, dT0, nullptr, Qb0, Sg0, nullptr, 128, 128, 0, 0};
    Pq.op[1] = {wq, bqp, dT1, nullptr, Qb1, Sg1, nullptr, 128, 128, 0, 0};
    Pq.op[2] = {wk, bkp, dT0, nullptr, Kt0, nullptr, nullptr, 128, 128, 0, 1};
    Pq.op[3] = {wk, bkp, dT1, nullptr, Kt1, nullptr, nullptr, 128, 128, 0, 1};
    Pq.op[4] = {wv, bvp, dT0, nullptr, Vb0, nullptr, nullptr, 128, 128, 0, 2};
    Pq.op[5] = {wv, bvp, dT1, nullptr, Vb1, nullptr, nullptr, 128, 128, 0, 2};
    mfma_gemm_kernel<<<dim3(16, 2, 6), 256, 0, stream>>>(Pq);

    attn_mfma_kernel<<<dim3(64, 8), 256, 0, stream>>>(
        Qb0, Kt0, Vb0, Qb1, Kt1, Vb1, mgT0, mgT1, cross);

    MOps8 P1 = {};
    P1.op[0] = {wmx, b1p, dT0, mgT0, HT0, Sg0, nullptr, 256, 128, 256, 5};
    P1.op[1] = {wmx, b1p, dT1, mgT1, HT1, Sg1, nullptr, 256, 128, 256, 5};
    mfma_gemm_kernel<<<dim3(16, 4, 2), 256, 0, stream>>>(P1);

    MOps8 P2 = {};
    P2.op[0] = {w2, b2p, HT0, nullptr, dT0, out0, Sg0, 256, 256, 128, 4};
    P2.op[1] = {w2, b2p, HT1, nullptr, dT1, out1, Sg1, 256, 256, 128, 4};
    mfma_gemm_kernel<<<dim3(16, 2, 2), 256, 0, stream>>>(P2);
  }
}